// Round 4
// baseline (858.220 us; speedup 1.0000x reference)
//
#include <hip/hip_runtime.h>
#include <math.h>

#define RDIM 128
#define CDIM 512
#define EDIM 768
#define HDIM 12
#define DDIM 64
#define MDIM (RDIM*CDIM)                  // 65536 tokens
#define OUT_ELEMS ((size_t)MDIM*EDIM)     // 50331648
#define HSTRIDE ((size_t)CDIM*RDIM*DDIM)  // 4194304 elems per head (512*8192)
#define WELEMS (EDIM*EDIM)                // 589824

typedef unsigned short ushort_t;
typedef __attribute__((ext_vector_type(8))) short bf16x8;
typedef __attribute__((ext_vector_type(8))) unsigned short u16x8;
typedef __attribute__((ext_vector_type(4))) float f32x4;

__device__ __forceinline__ ushort_t f2bf(float f) {
    unsigned u = __float_as_uint(f);
    unsigned r = u + 0x7fffu + ((u >> 16) & 1u);   // round-to-nearest-even
    return (ushort_t)(r >> 16);
}

__device__ __forceinline__ void gload16(const void* g, void* l) {
    __builtin_amdgcn_global_load_lds(
        (const __attribute__((address_space(1))) unsigned int*)g,
        (__attribute__((address_space(3))) unsigned int*)l, 16, 0, 0);
}

// ============================================================================
// cast x (fp32) -> bf16, 8 elems/thread
// ============================================================================
__global__ __launch_bounds__(256)
void cast_x(const float* __restrict__ x, ushort_t* __restrict__ xb) {
    size_t i = ((size_t)blockIdx.x * 256 + threadIdx.x) * 8;
    float4 a = *(const float4*)&x[i];
    float4 b = *(const float4*)&x[i + 4];
    u16x8 o;
    o[0]=f2bf(a.x); o[1]=f2bf(a.y); o[2]=f2bf(a.z); o[3]=f2bf(a.w);
    o[4]=f2bf(b.x); o[5]=f2bf(b.y); o[6]=f2bf(b.z); o[7]=f2bf(b.w);
    *(u16x8*)&xb[i] = o;
}

// ============================================================================
// W[k][n] fp32 -> Wt[n][k] bf16   (768x768)
// ============================================================================
__global__ __launch_bounds__(256)
void transpose_cast_w(const float* __restrict__ W, ushort_t* __restrict__ Wt) {
    __shared__ ushort_t t[64][66];
    const int k0 = blockIdx.x * 64, n0 = blockIdx.y * 64;
    const int tx = threadIdx.x & 15, ty = threadIdx.x >> 4;
    #pragma unroll
    for (int rep = 0; rep < 4; ++rep) {
        int k = ty + rep * 16;
        float4 v = *(const float4*)&W[(size_t)(k0 + k) * EDIM + n0 + tx*4];
        t[k][tx*4+0] = f2bf(v.x); t[k][tx*4+1] = f2bf(v.y);
        t[k][tx*4+2] = f2bf(v.z); t[k][tx*4+3] = f2bf(v.w);
    }
    __syncthreads();
    #pragma unroll
    for (int rep = 0; rep < 4; ++rep) {
        int n = ty + rep * 16;
        ushort4 o = { t[tx*4+0][n], t[tx*4+1][n], t[tx*4+2][n], t[tx*4+3][n] };
        *(ushort4*)&Wt[(size_t)(n0 + n) * EDIM + k0 + tx*4] = o;
    }
}

// ============================================================================
// concat biases -> bqkv[2304] fp32
// ============================================================================
__global__ __launch_bounds__(256)
void concat_bias(const float* __restrict__ bq, const float* __restrict__ bk,
                 const float* __restrict__ bv, float* __restrict__ bqkv) {
    int i = blockIdx.x * 256 + threadIdx.x;
    if (i < 768)        bqkv[i] = bq[i];
    else if (i < 1536)  bqkv[i] = bk[i - 768];
    else if (i < 2304)  bqkv[i] = bv[i - 1536];
}

// ============================================================================
// BT-GEMM: C[m][n] = sum_k A[m][k]*B[n][k]  (bf16 in, fp32 MFMA accumulate)
// 128x128 tile, BK=64, 4 waves (2x2), 16x16x32 MFMA. LDK = A/B row stride.
// Flat 1-D grid + bijective XCD swizzle (T1): w=(bid%8)*(NWG/8)+bid/8 so each
// XCD owns a contiguous work range with the REUSE dim innermost.
// MODE 1: out proj, fp32 + bias, work = m*6 + n           (NWG=3072)
// MODE 2: split-K logits, work = plane*16 + (y*4 + x)     (NWG=768)
// MODE 3: context, work = h*256 + rd*4 + i                (NWG=3072)
// MODE 4: fused QKV, work = m*18 + by                     (NWG=9216)
// ============================================================================
template<int M, int N, int K, int LDK, int MODE, int NWG>
__global__ __launch_bounds__(256)
void gemm_bt(const ushort_t* __restrict__ A, const ushort_t* __restrict__ B,
             const float* __restrict__ bias, float scale,
             float* __restrict__ outF, ushort_t* __restrict__ outB,
             size_t sAh, size_t sBh) {
    constexpr int SMEM_BYTES = (MODE == 4) ? 33280 : 32768;
    __shared__ __align__(16) char smem[SMEM_BYTES];
    ushort_t* As = (ushort_t*)smem;
    ushort_t* Bs = (ushort_t*)(smem + 16384);

    const int tid  = threadIdx.x;
    const int lane = tid & 63, wave = tid >> 6;
    const int wr = wave >> 1, wc = wave & 1;
    const int fr = lane & 15, fs = lane >> 4;

    // ---- XCD-aware work decode ----
    const int bid = blockIdx.x;
    const int w = (bid & 7) * (NWG / 8) + (bid >> 3);
    int bm, bn, h = 0, ksub = 0, plane = 0, by = 0;
    if (MODE == 4) {
        by = w % 18; bm = (w / 18) * 128; bn = by * 128;
    } else if (MODE == 2) {
        plane = w >> 4; h = plane >> 2; ksub = plane & 3;
        bm = (w & 3) * 128; bn = ((w >> 2) & 3) * 128;
    } else if (MODE == 3) {
        h = w >> 8; bm = (w & 3) * 128; bn = ((w >> 2) & 63) * 128;
    } else { // MODE 1
        bm = (w / 6) * 128; bn = (w % 6) * 128;
    }

    const ushort_t* Ab = A + (MODE == 2 || MODE == 3 ? (size_t)h * sAh : 0)
                           + (MODE == 2 ? (size_t)ksub * 2048 : 0)
                           + (size_t)bm * LDK;
    const ushort_t* Bb = B + (MODE == 2 || MODE == 3 ? (size_t)h * sBh : 0)
                           + (MODE == 2 ? (size_t)ksub * 2048 : 0)
                           + (size_t)bn * LDK;

    size_t goff[4];
    int loff[4];
    #pragma unroll
    for (int it = 0; it < 4; ++it) {
        int ci = it * 256 + tid;
        goff[it] = (size_t)(ci >> 3) * LDK + (ci & 7) * 8;
        loff[it] = ci * 16;
    }

    f32x4 acc[4][4];
    #pragma unroll
    for (int i = 0; i < 4; ++i)
        #pragma unroll
        for (int j = 0; j < 4; ++j) acc[i][j] = (f32x4){0.f, 0.f, 0.f, 0.f};

    for (int k0 = 0; k0 < K; k0 += 64) {
        #pragma unroll
        for (int it = 0; it < 4; ++it) {
            gload16(Ab + goff[it] + k0, (char*)smem + loff[it]);
            gload16(Bb + goff[it] + k0, (char*)smem + 16384 + loff[it]);
        }
        __syncthreads();
        #pragma unroll
        for (int kk = 0; kk < 2; ++kk) {
            bf16x8 af[4], bfr[4];
            #pragma unroll
            for (int mi = 0; mi < 4; ++mi)
                af[mi] = *(const bf16x8*)&As[(wr*64 + mi*16 + fr)*64 + kk*32 + fs*8];
            #pragma unroll
            for (int ni = 0; ni < 4; ++ni)
                bfr[ni] = *(const bf16x8*)&Bs[(wc*64 + ni*16 + fr)*64 + kk*32 + fs*8];
            #pragma unroll
            for (int mi = 0; mi < 4; ++mi)
                #pragma unroll
                for (int ni = 0; ni < 4; ++ni)
                    acc[mi][ni] = __builtin_amdgcn_mfma_f32_16x16x32_bf16(
                        af[mi], bfr[ni], acc[mi][ni], 0, 0, 0);
        }
        __syncthreads();
    }

    if (MODE == 4) {
        const int which = by / 6;                  // 0=Q,1=K,2=V (block-uniform)
        const int nb = (by % 6) * 128;             // hcol base
        if (which < 2) {
            ushort_t* dst = outB + (size_t)which * OUT_ELEMS;
            const float sc = (which == 0) ? scale : 1.f;
            #pragma unroll
            for (int mi = 0; mi < 4; ++mi) {
                #pragma unroll
                for (int ni = 0; ni < 4; ++ni) {
                    const int hcol = nb + wc*64 + ni*16 + fr;
                    const float bv = bias[which*768 + hcol];
                    const int hh = hcol >> 6, d = hcol & 63;
                    #pragma unroll
                    for (int j = 0; j < 4; ++j) {
                        const int m = bm + wr*64 + mi*16 + fs*4 + j;
                        float v = (acc[mi][ni][j] + bv) * sc;
                        size_t addr = (size_t)hh * HSTRIDE
                                    + (size_t)(m & 511) * 8192 + (m >> 9) * 64 + d;
                        dst[addr] = f2bf(v);
                    }
                }
            }
        } else {
            // V: transpose through LDS, coalesced stores to Vt[h][rd][j]
            ushort_t* Ts = (ushort_t*)smem;        // [128][130]
            __syncthreads();
            #pragma unroll
            for (int mi = 0; mi < 4; ++mi) {
                #pragma unroll
                for (int ni = 0; ni < 4; ++ni) {
                    const int nl = wc*64 + ni*16 + fr;
                    const float bv = bias[1536 + nb + nl];
                    #pragma unroll
                    for (int j = 0; j < 4; ++j) {
                        const int ml = wr*64 + mi*16 + fs*4 + j;
                        Ts[nl*130 + ml] = f2bf(acc[mi][ni][j] + bv);
                    }
                }
            }
            __syncthreads();
            ushort_t* dst = outB + 2 * OUT_ELEMS;
            const int base_h = nb >> 6;
            const int rblk = bm >> 9, jb = bm & 511;
            #pragma unroll
            for (int it = 0; it < 8; ++it) {
                const int idx = it * 256 + tid;
                const int row = idx >> 4, col8 = (idx & 15) * 8;
                const int hh = base_h + (row >> 6), d = row & 63;
                uint4 wv;
                wv.x = *(const uint*)&Ts[row*130 + col8];
                wv.y = *(const uint*)&Ts[row*130 + col8 + 2];
                wv.z = *(const uint*)&Ts[row*130 + col8 + 4];
                wv.w = *(const uint*)&Ts[row*130 + col8 + 6];
                size_t addr = (size_t)hh * HSTRIDE
                            + (size_t)(rblk*64 + d) * CDIM + jb + col8;
                *(uint4*)&dst[addr] = wv;
            }
        }
        return;
    }

    #pragma unroll
    for (int mi = 0; mi < 4; ++mi) {
        #pragma unroll
        for (int ni = 0; ni < 4; ++ni) {
            const int n = bn + wc*64 + ni*16 + fr;
            float bv = (MODE == 1) ? bias[n] : 0.f;
            #pragma unroll
            for (int j = 0; j < 4; ++j) {
                const int m = bm + wr*64 + mi*16 + fs*4 + j;
                float v = acc[mi][ni][j];
                if (MODE == 1) {
                    outF[(size_t)m * N + n] = v + bv;
                } else if (MODE == 2) {
                    outF[(size_t)plane * (CDIM*CDIM) + (size_t)m * CDIM + n] = v;
                } else { // MODE 3
                    size_t addr = ((size_t)(n >> 6) * CDIM + m) * EDIM
                                + h * DDIM + (n & 63);
                    outB[addr] = f2bf(v);
                }
            }
        }
    }
}

// ============================================================================
// softmax over 512 cols for H*C rows; sums 4 split-K partials first.
// fp32 probs -> attn (d_out), bf16 copy -> Pb.
// ============================================================================
__global__ __launch_bounds__(256)
void softmax_reduce(const float* __restrict__ part, float* __restrict__ attn,
                    ushort_t* __restrict__ Pb) {
    const int row = blockIdx.x;              // h*512 + c
    const int h = row >> 9, c = row & 511;
    const int tid = threadIdx.x;
    const int lane = tid & 63, wid = tid >> 6;
    __shared__ float red[8];

    float v0 = 0.f, v1 = 0.f;
    #pragma unroll
    for (int s = 0; s < 4; ++s) {
        const float* p = part + ((size_t)(h*4 + s) * (CDIM*CDIM)) + (size_t)c * CDIM;
        v0 += p[tid];
        v1 += p[tid + 256];
    }
    float m = fmaxf(v0, v1);
    #pragma unroll
    for (int off = 32; off > 0; off >>= 1) m = fmaxf(m, __shfl_down(m, off));
    if (lane == 0) red[wid] = m;
    __syncthreads();
    if (tid == 0) red[4] = fmaxf(fmaxf(red[0], red[1]), fmaxf(red[2], red[3]));
    __syncthreads();
    const float M = red[4];

    float e0 = expf(v0 - M), e1 = expf(v1 - M);
    float s = e0 + e1;
    #pragma unroll
    for (int off = 32; off > 0; off >>= 1) s += __shfl_down(s, off);
    __syncthreads();
    if (lane == 0) red[wid] = s;
    __syncthreads();
    if (tid == 0) red[5] = red[0] + red[1] + red[2] + red[3];
    __syncthreads();
    const float inv = 1.f / red[5];
    float o0 = e0 * inv, o1 = e1 * inv;
    float* pout = attn + (size_t)row * CDIM;
    ushort_t* pb = Pb + (size_t)row * CDIM;
    pout[tid] = o0;        pout[tid + 256] = o1;
    pb[tid]   = f2bf(o0);  pb[tid + 256]   = f2bf(o1);
}

// ============================================================================
extern "C" void kernel_launch(void* const* d_in, const int* in_sizes, int n_in,
                              void* d_out, int out_size, void* d_ws, size_t ws_size,
                              hipStream_t stream) {
    const float* x  = (const float*)d_in[0];
    const float* Wq = (const float*)d_in[1];
    const float* bq = (const float*)d_in[2];
    const float* Wk = (const float*)d_in[3];
    const float* bk = (const float*)d_in[4];
    const float* Wv = (const float*)d_in[5];
    const float* bv = (const float*)d_in[6];
    const float* Wo = (const float*)d_in[7];
    const float* bo = (const float*)d_in[8];

    float* out   = (float*)d_out;
    float* attnp = out + OUT_ELEMS;            // attn_probs fp32 output region

    // workspace layout (ushort units)
    ushort_t* ws   = (ushort_t*)d_ws;
    ushort_t* xb   = ws;                                   // 100 MB; reused as ctxb
    ushort_t* Wqkv = xb + OUT_ELEMS;                       // [2304][768]
    ushort_t* Wto  = Wqkv + 3*WELEMS;
    float*    bqkv = (float*)(Wto + WELEMS);               // 2304 fp32
    ushort_t* Qp   = Wto + WELEMS + 4608;                  // [12][512][8192]
    ushort_t* Kp   = Qp + OUT_ELEMS;                       // contiguous after Qp
    ushort_t* Vt   = Kp + OUT_ELEMS;                       // [12][8192][512]
    ushort_t* Pb   = Vt + OUT_ELEMS;                       // [12][512][512]
    float*    part = (float*)(Pb + (size_t)HDIM*CDIM*CDIM); // 48 planes fp32
    ushort_t* ctxb = xb;                                   // reuse after QKV GEMM

    const float scaling = 0.011048543456039806f;  // 64^-0.5 / sqrt(128)

    // 1. casts / weight transposes / bias concat
    cast_x<<<MDIM*EDIM/(256*8), 256, 0, stream>>>(x, xb);
    dim3 wt(EDIM/64, EDIM/64);
    transpose_cast_w<<<wt, 256, 0, stream>>>(Wq, Wqkv);
    transpose_cast_w<<<wt, 256, 0, stream>>>(Wk, Wqkv + WELEMS);
    transpose_cast_w<<<wt, 256, 0, stream>>>(Wv, Wqkv + 2*WELEMS);
    transpose_cast_w<<<wt, 256, 0, stream>>>(Wo, Wto);
    concat_bias<<<9, 256, 0, stream>>>(bq, bk, bv, bqkv);

    // 2. fused QKV projection (Q,K per-head; V direct-transposed)
    gemm_bt<MDIM, 2304, EDIM, EDIM, 4, 9216><<<9216, 256, 0, stream>>>(
        xb, Wqkv, bqkv, scaling, nullptr, Qp, 0, 0);

    // 3. attn logits, split-K=4: per head 512x512, K-chunks of 2048
    gemm_bt<CDIM, CDIM, 2048, 8192, 2, 768><<<768, 256, 0, stream>>>(
        Qp, Kp, nullptr, 1.f, part, nullptr, HSTRIDE, HSTRIDE);

    // 4. softmax (+4-way partial reduce), fp32 out + bf16 copy
    softmax_reduce<<<HDIM*CDIM, 256, 0, stream>>>(part, attnp, Pb);

    // 5. context: per head 512x8192xK512 -> bf16 token-major
    gemm_bt<CDIM, 8192, CDIM, CDIM, 3, 3072><<<3072, 256, 0, stream>>>(
        Pb, Vt, nullptr, 1.f, nullptr, ctxb, (size_t)CDIM*CDIM, HSTRIDE);

    // 6. output projection (fp32 + bias)
    gemm_bt<MDIM, EDIM, EDIM, EDIM, 1, 3072><<<3072, 256, 0, stream>>>(
        ctxb, Wto, bo, 1.f, out, nullptr, 0, 0);
}

// Round 5
// 725.097 us; speedup vs baseline: 1.1836x; 1.1836x over previous
//
#include <hip/hip_runtime.h>
#include <math.h>

#define RDIM 128
#define CDIM 512
#define EDIM 768
#define HDIM 12
#define DDIM 64
#define MDIM (RDIM*CDIM)                  // 65536 tokens
#define OUT_ELEMS ((size_t)MDIM*EDIM)     // 50331648
#define HSTRIDE ((size_t)CDIM*RDIM*DDIM)  // 4194304 elems per head (512*8192)
#define WELEMS (EDIM*EDIM)                // 589824

typedef unsigned short ushort_t;
typedef __attribute__((ext_vector_type(8))) short bf16x8;
typedef __attribute__((ext_vector_type(8))) unsigned short u16x8;
typedef __attribute__((ext_vector_type(4))) float f32x4;

__device__ __forceinline__ ushort_t f2bf(float f) {
    unsigned u = __float_as_uint(f);
    unsigned r = u + 0x7fffu + ((u >> 16) & 1u);   // round-to-nearest-even
    return (ushort_t)(r >> 16);
}

__device__ __forceinline__ void gload16(const void* g, void* l) {
    __builtin_amdgcn_global_load_lds(
        (const __attribute__((address_space(1))) unsigned int*)g,
        (__attribute__((address_space(3))) unsigned int*)l, 16, 0, 0);
}

// ============================================================================
// cast x (fp32) -> bf16, 8 elems/thread
// ============================================================================
__global__ __launch_bounds__(256)
void cast_x(const float* __restrict__ x, ushort_t* __restrict__ xb) {
    size_t i = ((size_t)blockIdx.x * 256 + threadIdx.x) * 8;
    float4 a = *(const float4*)&x[i];
    float4 b = *(const float4*)&x[i + 4];
    u16x8 o;
    o[0]=f2bf(a.x); o[1]=f2bf(a.y); o[2]=f2bf(a.z); o[3]=f2bf(a.w);
    o[4]=f2bf(b.x); o[5]=f2bf(b.y); o[6]=f2bf(b.z); o[7]=f2bf(b.w);
    *(u16x8*)&xb[i] = o;
}

// ============================================================================
// W[k][n] fp32 -> Wt[n][k] bf16   (768x768)
// ============================================================================
__global__ __launch_bounds__(256)
void transpose_cast_w(const float* __restrict__ W, ushort_t* __restrict__ Wt) {
    __shared__ ushort_t t[64][66];
    const int k0 = blockIdx.x * 64, n0 = blockIdx.y * 64;
    const int tx = threadIdx.x & 15, ty = threadIdx.x >> 4;
    #pragma unroll
    for (int rep = 0; rep < 4; ++rep) {
        int k = ty + rep * 16;
        float4 v = *(const float4*)&W[(size_t)(k0 + k) * EDIM + n0 + tx*4];
        t[k][tx*4+0] = f2bf(v.x); t[k][tx*4+1] = f2bf(v.y);
        t[k][tx*4+2] = f2bf(v.z); t[k][tx*4+3] = f2bf(v.w);
    }
    __syncthreads();
    #pragma unroll
    for (int rep = 0; rep < 4; ++rep) {
        int n = ty + rep * 16;
        ushort4 o = { t[tx*4+0][n], t[tx*4+1][n], t[tx*4+2][n], t[tx*4+3][n] };
        *(ushort4*)&Wt[(size_t)(n0 + n) * EDIM + k0 + tx*4] = o;
    }
}

// ============================================================================
// concat biases -> bqkv[2304] fp32
// ============================================================================
__global__ __launch_bounds__(256)
void concat_bias(const float* __restrict__ bq, const float* __restrict__ bk,
                 const float* __restrict__ bv, float* __restrict__ bqkv) {
    int i = blockIdx.x * 256 + threadIdx.x;
    if (i < 768)        bqkv[i] = bq[i];
    else if (i < 1536)  bqkv[i] = bk[i - 768];
    else if (i < 2304)  bqkv[i] = bv[i - 1536];
}

// ============================================================================
// BT-GEMM: C[m][n] = sum_k A[m][k]*B[n][k]  (bf16 in, fp32 MFMA accumulate)
// 128x128 tile, BK=64, 4 waves (2x2), 16x16x32 MFMA. LDK = A/B row stride.
// T3-minimum pipeline: explicit LDS double-buffer (2x32KB); next tile's
// global_load_lds issued BEFORE current tile's ds_read+MFMA; ONE barrier
// per K-step (its implicit vmcnt(0) sits a full compute-phase after issue).
// Flat 1-D grid + bijective XCD swizzle (T1), reuse dim innermost.
// MODE 1: out proj, fp32 + bias, work = m*6 + n           (NWG=3072)
// MODE 2: split-K logits, work = plane*16 + (y*4 + x)     (NWG=768)
// MODE 3: context, work = h*256 + rd*4 + i                (NWG=3072)
// MODE 4: fused QKV, work = m*18 + by                     (NWG=9216)
// ============================================================================
template<int M, int N, int K, int LDK, int MODE, int NWG>
__global__ __launch_bounds__(256)
void gemm_bt(const ushort_t* __restrict__ A, const ushort_t* __restrict__ B,
             const float* __restrict__ bias, float scale,
             float* __restrict__ outF, ushort_t* __restrict__ outB,
             size_t sAh, size_t sBh) {
    constexpr int BUFB = 32768;
    __shared__ __align__(16) char smem[2 * BUFB];   // dbuf; V-epilogue reuses 33280B

    const int tid  = threadIdx.x;
    const int lane = tid & 63, wave = tid >> 6;
    const int wr = wave >> 1, wc = wave & 1;
    const int fr = lane & 15, fs = lane >> 4;

    // ---- XCD-aware work decode ----
    const int bid = blockIdx.x;
    const int w = (bid & 7) * (NWG / 8) + (bid >> 3);
    int bm, bn, h = 0, ksub = 0, plane = 0, by = 0;
    if (MODE == 4) {
        by = w % 18; bm = (w / 18) * 128; bn = by * 128;
    } else if (MODE == 2) {
        plane = w >> 4; h = plane >> 2; ksub = plane & 3;
        bm = (w & 3) * 128; bn = ((w >> 2) & 3) * 128;
    } else if (MODE == 3) {
        h = w >> 8; bm = (w & 3) * 128; bn = ((w >> 2) & 63) * 128;
    } else { // MODE 1
        bm = (w / 6) * 128; bn = (w % 6) * 128;
    }

    const ushort_t* Ab = A + (MODE == 2 || MODE == 3 ? (size_t)h * sAh : 0)
                           + (MODE == 2 ? (size_t)ksub * 2048 : 0)
                           + (size_t)bm * LDK;
    const ushort_t* Bb = B + (MODE == 2 || MODE == 3 ? (size_t)h * sBh : 0)
                           + (MODE == 2 ? (size_t)ksub * 2048 : 0)
                           + (size_t)bn * LDK;

    size_t goff[4];
    int loff[4];
    #pragma unroll
    for (int it = 0; it < 4; ++it) {
        int ci = it * 256 + tid;
        goff[it] = (size_t)(ci >> 3) * LDK + (ci & 7) * 8;
        loff[it] = ci * 16;
    }

    f32x4 acc[4][4];
    #pragma unroll
    for (int i = 0; i < 4; ++i)
        #pragma unroll
        for (int j = 0; j < 4; ++j) acc[i][j] = (f32x4){0.f, 0.f, 0.f, 0.f};

    constexpr int NT = K / 64;

    // prologue: stage tile 0 into buf 0
    #pragma unroll
    for (int it = 0; it < 4; ++it) {
        gload16(Ab + goff[it], smem + loff[it]);
        gload16(Bb + goff[it], smem + 16384 + loff[it]);
    }
    __syncthreads();

    int cur = 0;
    for (int t = 0; t < NT; ++t) {
        if (t + 1 < NT) {
            const int k0 = (t + 1) * 64;
            char* dst = smem + (cur ^ 1) * BUFB;
            #pragma unroll
            for (int it = 0; it < 4; ++it) {
                gload16(Ab + goff[it] + k0, dst + loff[it]);
                gload16(Bb + goff[it] + k0, dst + 16384 + loff[it]);
            }
        }
        const ushort_t* As = (const ushort_t*)(smem + cur * BUFB);
        const ushort_t* Bs = (const ushort_t*)(smem + cur * BUFB + 16384);
        #pragma unroll
        for (int kk = 0; kk < 2; ++kk) {
            bf16x8 af[4], bfr[4];
            #pragma unroll
            for (int mi = 0; mi < 4; ++mi)
                af[mi] = *(const bf16x8*)&As[(wr*64 + mi*16 + fr)*64 + kk*32 + fs*8];
            #pragma unroll
            for (int ni = 0; ni < 4; ++ni)
                bfr[ni] = *(const bf16x8*)&Bs[(wc*64 + ni*16 + fr)*64 + kk*32 + fs*8];
            #pragma unroll
            for (int mi = 0; mi < 4; ++mi)
                #pragma unroll
                for (int ni = 0; ni < 4; ++ni)
                    acc[mi][ni] = __builtin_amdgcn_mfma_f32_16x16x32_bf16(
                        af[mi], bfr[ni], acc[mi][ni], 0, 0, 0);
        }
        __syncthreads();   // implicit vmcnt(0)+lgkmcnt(0): next buf ready, cur free
        cur ^= 1;
    }

    if (MODE == 4) {
        const int which = by / 6;                  // 0=Q,1=K,2=V (block-uniform)
        const int nb = (by % 6) * 128;             // hcol base
        if (which < 2) {
            ushort_t* dst = outB + (size_t)which * OUT_ELEMS;
            const float sc = (which == 0) ? scale : 1.f;
            #pragma unroll
            for (int mi = 0; mi < 4; ++mi) {
                #pragma unroll
                for (int ni = 0; ni < 4; ++ni) {
                    const int hcol = nb + wc*64 + ni*16 + fr;
                    const float bv = bias[which*768 + hcol];
                    const int hh = hcol >> 6, d = hcol & 63;
                    #pragma unroll
                    for (int j = 0; j < 4; ++j) {
                        const int m = bm + wr*64 + mi*16 + fs*4 + j;
                        float v = (acc[mi][ni][j] + bv) * sc;
                        size_t addr = (size_t)hh * HSTRIDE
                                    + (size_t)(m & 511) * 8192 + (m >> 9) * 64 + d;
                        dst[addr] = f2bf(v);
                    }
                }
            }
        } else {
            // V: transpose through LDS, coalesced stores to Vt[h][rd][j]
            ushort_t* Ts = (ushort_t*)smem;        // [128][130] = 33280B < 64KB
            __syncthreads();
            #pragma unroll
            for (int mi = 0; mi < 4; ++mi) {
                #pragma unroll
                for (int ni = 0; ni < 4; ++ni) {
                    const int nl = wc*64 + ni*16 + fr;
                    const float bv = bias[1536 + nb + nl];
                    #pragma unroll
                    for (int j = 0; j < 4; ++j) {
                        const int ml = wr*64 + mi*16 + fs*4 + j;
                        Ts[nl*130 + ml] = f2bf(acc[mi][ni][j] + bv);
                    }
                }
            }
            __syncthreads();
            ushort_t* dst = outB + 2 * OUT_ELEMS;
            const int base_h = nb >> 6;
            const int rblk = bm >> 9, jb = bm & 511;
            #pragma unroll
            for (int it = 0; it < 8; ++it) {
                const int idx = it * 256 + tid;
                const int row = idx >> 4, col8 = (idx & 15) * 8;
                const int hh = base_h + (row >> 6), d = row & 63;
                uint4 wv;
                wv.x = *(const uint*)&Ts[row*130 + col8];
                wv.y = *(const uint*)&Ts[row*130 + col8 + 2];
                wv.z = *(const uint*)&Ts[row*130 + col8 + 4];
                wv.w = *(const uint*)&Ts[row*130 + col8 + 6];
                size_t addr = (size_t)hh * HSTRIDE
                            + (size_t)(rblk*64 + d) * CDIM + jb + col8;
                *(uint4*)&dst[addr] = wv;
            }
        }
        return;
    }

    #pragma unroll
    for (int mi = 0; mi < 4; ++mi) {
        #pragma unroll
        for (int ni = 0; ni < 4; ++ni) {
            const int n = bn + wc*64 + ni*16 + fr;
            float bv = (MODE == 1) ? bias[n] : 0.f;
            #pragma unroll
            for (int j = 0; j < 4; ++j) {
                const int m = bm + wr*64 + mi*16 + fs*4 + j;
                float v = acc[mi][ni][j];
                if (MODE == 1) {
                    outF[(size_t)m * N + n] = v + bv;
                } else if (MODE == 2) {
                    outF[(size_t)plane * (CDIM*CDIM) + (size_t)m * CDIM + n] = v;
                } else { // MODE 3
                    size_t addr = ((size_t)(n >> 6) * CDIM + m) * EDIM
                                + h * DDIM + (n & 63);
                    outB[addr] = f2bf(v);
                }
            }
        }
    }
}

// ============================================================================
// softmax over 512 cols for H*C rows; sums 4 split-K partials first.
// fp32 probs -> attn (d_out), bf16 copy -> Pb.
// ============================================================================
__global__ __launch_bounds__(256)
void softmax_reduce(const float* __restrict__ part, float* __restrict__ attn,
                    ushort_t* __restrict__ Pb) {
    const int row = blockIdx.x;              // h*512 + c
    const int h = row >> 9, c = row & 511;
    const int tid = threadIdx.x;
    const int lane = tid & 63, wid = tid >> 6;
    __shared__ float red[8];

    float v0 = 0.f, v1 = 0.f;
    #pragma unroll
    for (int s = 0; s < 4; ++s) {
        const float* p = part + ((size_t)(h*4 + s) * (CDIM*CDIM)) + (size_t)c * CDIM;
        v0 += p[tid];
        v1 += p[tid + 256];
    }
    float m = fmaxf(v0, v1);
    #pragma unroll
    for (int off = 32; off > 0; off >>= 1) m = fmaxf(m, __shfl_down(m, off));
    if (lane == 0) red[wid] = m;
    __syncthreads();
    if (tid == 0) red[4] = fmaxf(fmaxf(red[0], red[1]), fmaxf(red[2], red[3]));
    __syncthreads();
    const float M = red[4];

    float e0 = expf(v0 - M), e1 = expf(v1 - M);
    float s = e0 + e1;
    #pragma unroll
    for (int off = 32; off > 0; off >>= 1) s += __shfl_down(s, off);
    __syncthreads();
    if (lane == 0) red[wid] = s;
    __syncthreads();
    if (tid == 0) red[5] = red[0] + red[1] + red[2] + red[3];
    __syncthreads();
    const float inv = 1.f / red[5];
    float o0 = e0 * inv, o1 = e1 * inv;
    float* pout = attn + (size_t)row * CDIM;
    ushort_t* pb = Pb + (size_t)row * CDIM;
    pout[tid] = o0;        pout[tid + 256] = o1;
    pb[tid]   = f2bf(o0);  pb[tid + 256]   = f2bf(o1);
}

// ============================================================================
extern "C" void kernel_launch(void* const* d_in, const int* in_sizes, int n_in,
                              void* d_out, int out_size, void* d_ws, size_t ws_size,
                              hipStream_t stream) {
    const float* x  = (const float*)d_in[0];
    const float* Wq = (const float*)d_in[1];
    const float* bq = (const float*)d_in[2];
    const float* Wk = (const float*)d_in[3];
    const float* bk = (const float*)d_in[4];
    const float* Wv = (const float*)d_in[5];
    const float* bv = (const float*)d_in[6];
    const float* Wo = (const float*)d_in[7];
    const float* bo = (const float*)d_in[8];

    float* out   = (float*)d_out;
    float* attnp = out + OUT_ELEMS;            // attn_probs fp32 output region

    // workspace layout (ushort units)
    ushort_t* ws   = (ushort_t*)d_ws;
    ushort_t* xb   = ws;                                   // 100 MB; reused as ctxb
    ushort_t* Wqkv = xb + OUT_ELEMS;                       // [2304][768]
    ushort_t* Wto  = Wqkv + 3*WELEMS;
    float*    bqkv = (float*)(Wto + WELEMS);               // 2304 fp32
    ushort_t* Qp   = Wto + WELEMS + 4608;                  // [12][512][8192]
    ushort_t* Kp   = Qp + OUT_ELEMS;                       // contiguous after Qp
    ushort_t* Vt   = Kp + OUT_ELEMS;                       // [12][8192][512]
    ushort_t* Pb   = Vt + OUT_ELEMS;                       // [12][512][512]
    float*    part = (float*)(Pb + (size_t)HDIM*CDIM*CDIM); // 48 planes fp32
    ushort_t* ctxb = xb;                                   // reuse after QKV GEMM

    const float scaling = 0.011048543456039806f;  // 64^-0.5 / sqrt(128)

    // 1. casts / weight transposes / bias concat
    cast_x<<<MDIM*EDIM/(256*8), 256, 0, stream>>>(x, xb);
    dim3 wt(EDIM/64, EDIM/64);
    transpose_cast_w<<<wt, 256, 0, stream>>>(Wq, Wqkv);
    transpose_cast_w<<<wt, 256, 0, stream>>>(Wk, Wqkv + WELEMS);
    transpose_cast_w<<<wt, 256, 0, stream>>>(Wv, Wqkv + 2*WELEMS);
    transpose_cast_w<<<wt, 256, 0, stream>>>(Wo, Wto);
    concat_bias<<<9, 256, 0, stream>>>(bq, bk, bv, bqkv);

    // 2. fused QKV projection (Q,K per-head; V direct-transposed)
    gemm_bt<MDIM, 2304, EDIM, EDIM, 4, 9216><<<9216, 256, 0, stream>>>(
        xb, Wqkv, bqkv, scaling, nullptr, Qp, 0, 0);

    // 3. attn logits, split-K=4: per head 512x512, K-chunks of 2048
    gemm_bt<CDIM, CDIM, 2048, 8192, 2, 768><<<768, 256, 0, stream>>>(
        Qp, Kp, nullptr, 1.f, part, nullptr, HSTRIDE, HSTRIDE);

    // 4. softmax (+4-way partial reduce), fp32 out + bf16 copy
    softmax_reduce<<<HDIM*CDIM, 256, 0, stream>>>(part, attnp, Pb);

    // 5. context: per head 512x8192xK512 -> bf16 token-major
    gemm_bt<CDIM, 8192, CDIM, CDIM, 3, 3072><<<3072, 256, 0, stream>>>(
        Pb, Vt, nullptr, 1.f, nullptr, ctxb, (size_t)CDIM*CDIM, HSTRIDE);

    // 6. output projection (fp32 + bias)
    gemm_bt<MDIM, EDIM, EDIM, EDIM, 1, 3072><<<3072, 256, 0, stream>>>(
        ctxb, Wto, bo, 1.f, out, nullptr, 0, 0);
}

// Round 6
// 707.231 us; speedup vs baseline: 1.2135x; 1.0253x over previous
//
#include <hip/hip_runtime.h>
#include <math.h>

#define RDIM 128
#define CDIM 512
#define EDIM 768
#define HDIM 12
#define DDIM 64
#define MDIM (RDIM*CDIM)                  // 65536 tokens
#define OUT_ELEMS ((size_t)MDIM*EDIM)     // 50331648
#define HSTRIDE ((size_t)CDIM*RDIM*DDIM)  // 4194304 elems per head (512*8192)
#define WELEMS (EDIM*EDIM)                // 589824

typedef unsigned short ushort_t;
typedef __attribute__((ext_vector_type(8))) short bf16x8;
typedef __attribute__((ext_vector_type(8))) unsigned short u16x8;
typedef __attribute__((ext_vector_type(4))) float f32x4;

__device__ __forceinline__ ushort_t f2bf(float f) {
    unsigned u = __float_as_uint(f);
    unsigned r = u + 0x7fffu + ((u >> 16) & 1u);   // round-to-nearest-even
    return (ushort_t)(r >> 16);
}

__device__ __forceinline__ void gload16(const void* g, void* l) {
    __builtin_amdgcn_global_load_lds(
        (const __attribute__((address_space(1))) unsigned int*)g,
        (__attribute__((address_space(3))) unsigned int*)l, 16, 0, 0);
}

// ============================================================================
// cast x (fp32) -> bf16, 8 elems/thread
// ============================================================================
__global__ __launch_bounds__(256)
void cast_x(const float* __restrict__ x, ushort_t* __restrict__ xb) {
    size_t i = ((size_t)blockIdx.x * 256 + threadIdx.x) * 8;
    float4 a = *(const float4*)&x[i];
    float4 b = *(const float4*)&x[i + 4];
    u16x8 o;
    o[0]=f2bf(a.x); o[1]=f2bf(a.y); o[2]=f2bf(a.z); o[3]=f2bf(a.w);
    o[4]=f2bf(b.x); o[5]=f2bf(b.y); o[6]=f2bf(b.z); o[7]=f2bf(b.w);
    *(u16x8*)&xb[i] = o;
}

// ============================================================================
// W[k][n] fp32 -> Wt[n][k] bf16   (768x768)
// ============================================================================
__global__ __launch_bounds__(256)
void transpose_cast_w(const float* __restrict__ W, ushort_t* __restrict__ Wt) {
    __shared__ ushort_t t[64][66];
    const int k0 = blockIdx.x * 64, n0 = blockIdx.y * 64;
    const int tx = threadIdx.x & 15, ty = threadIdx.x >> 4;
    #pragma unroll
    for (int rep = 0; rep < 4; ++rep) {
        int k = ty + rep * 16;
        float4 v = *(const float4*)&W[(size_t)(k0 + k) * EDIM + n0 + tx*4];
        t[k][tx*4+0] = f2bf(v.x); t[k][tx*4+1] = f2bf(v.y);
        t[k][tx*4+2] = f2bf(v.z); t[k][tx*4+3] = f2bf(v.w);
    }
    __syncthreads();
    #pragma unroll
    for (int rep = 0; rep < 4; ++rep) {
        int n = ty + rep * 16;
        ushort4 o = { t[tx*4+0][n], t[tx*4+1][n], t[tx*4+2][n], t[tx*4+3][n] };
        *(ushort4*)&Wt[(size_t)(n0 + n) * EDIM + k0 + tx*4] = o;
    }
}

// ============================================================================
// concat biases -> bqkv[2304] fp32
// ============================================================================
__global__ __launch_bounds__(256)
void concat_bias(const float* __restrict__ bq, const float* __restrict__ bk,
                 const float* __restrict__ bv, float* __restrict__ bqkv) {
    int i = blockIdx.x * 256 + threadIdx.x;
    if (i < 768)        bqkv[i] = bq[i];
    else if (i < 1536)  bqkv[i] = bk[i - 768];
    else if (i < 2304)  bqkv[i] = bv[i - 1536];
}

// ============================================================================
// BT-GEMM: C[m][n] = sum_k A[m][k]*B[n][k]  (bf16 in, fp32 MFMA accumulate)
// 128x128 tile, BK=64, 4 waves (2x2), 16x16x32 MFMA. LDK = A/B row stride.
// T3-minimum pipeline: explicit LDS double-buffer (2x32KB); next tile's
// global_load_lds issued BEFORE current tile's ds_read+MFMA; ONE barrier/step.
// T2 LDS swizzle (both-sides, rule #21): LDS dest stays LINEAR for
// global_load_lds; the global SOURCE chunk is pre-permuted seg^=(row&7) and
// the ds_read address applies the same XOR ((fr&7)<<3 elems) -> each wave64
// ds_read_b128 spreads over all 32 banks (8 dwords/bank = conflict-free).
// Flat 1-D grid + bijective XCD swizzle (T1), reuse dim innermost.
// MODE 1: out proj, fp32 + bias, work = m*6 + n           (NWG=3072)
// MODE 2: split-K logits, work = plane*16 + (y*4 + x)     (NWG=768)
// MODE 3: context, work = h*256 + rd*4 + i                (NWG=3072)
// MODE 4: fused QKV, work = m*18 + by                     (NWG=9216)
// ============================================================================
template<int M, int N, int K, int LDK, int MODE, int NWG>
__global__ __launch_bounds__(256)
void gemm_bt(const ushort_t* __restrict__ A, const ushort_t* __restrict__ B,
             const float* __restrict__ bias, float scale,
             float* __restrict__ outF, ushort_t* __restrict__ outB,
             size_t sAh, size_t sBh) {
    constexpr int BUFB = 32768;
    __shared__ __align__(16) char smem[2 * BUFB];   // dbuf; V-epilogue reuses 33280B

    const int tid  = threadIdx.x;
    const int lane = tid & 63, wave = tid >> 6;
    const int wr = wave >> 1, wc = wave & 1;
    const int fr = lane & 15, fs = lane >> 4;
    const int sw = (fr & 7) << 3;                   // T2 read-side XOR (elems)

    // ---- XCD-aware work decode ----
    const int bid = blockIdx.x;
    const int w = (bid & 7) * (NWG / 8) + (bid >> 3);
    int bm, bn, h = 0, ksub = 0, plane = 0, by = 0;
    if (MODE == 4) {
        by = w % 18; bm = (w / 18) * 128; bn = by * 128;
    } else if (MODE == 2) {
        plane = w >> 4; h = plane >> 2; ksub = plane & 3;
        bm = (w & 3) * 128; bn = ((w >> 2) & 3) * 128;
    } else if (MODE == 3) {
        h = w >> 8; bm = (w & 3) * 128; bn = ((w >> 2) & 63) * 128;
    } else { // MODE 1
        bm = (w / 6) * 128; bn = (w % 6) * 128;
    }

    const ushort_t* Ab = A + (MODE == 2 || MODE == 3 ? (size_t)h * sAh : 0)
                           + (MODE == 2 ? (size_t)ksub * 2048 : 0)
                           + (size_t)bm * LDK;
    const ushort_t* Bb = B + (MODE == 2 || MODE == 3 ? (size_t)h * sBh : 0)
                           + (MODE == 2 ? (size_t)ksub * 2048 : 0)
                           + (size_t)bn * LDK;

    // staging map: LDS chunk ci (row=ci>>3, seg=ci&7) holds global chunk
    // seg ^ (row&7)  -> inverse-swizzled source, linear LDS dest
    size_t goff[4];
    int loff[4];
    #pragma unroll
    for (int it = 0; it < 4; ++it) {
        int ci = it * 256 + tid;
        int row = ci >> 3, seg = ci & 7;
        goff[it] = (size_t)row * LDK + (size_t)((seg ^ (row & 7)) * 8);
        loff[it] = ci * 16;
    }

    f32x4 acc[4][4];
    #pragma unroll
    for (int i = 0; i < 4; ++i)
        #pragma unroll
        for (int j = 0; j < 4; ++j) acc[i][j] = (f32x4){0.f, 0.f, 0.f, 0.f};

    constexpr int NT = K / 64;

    // prologue: stage tile 0 into buf 0
    #pragma unroll
    for (int it = 0; it < 4; ++it) {
        gload16(Ab + goff[it], smem + loff[it]);
        gload16(Bb + goff[it], smem + 16384 + loff[it]);
    }
    __syncthreads();

    int cur = 0;
    for (int t = 0; t < NT; ++t) {
        if (t + 1 < NT) {
            const int k0 = (t + 1) * 64;
            char* dst = smem + (cur ^ 1) * BUFB;
            #pragma unroll
            for (int it = 0; it < 4; ++it) {
                gload16(Ab + goff[it] + k0, dst + loff[it]);
                gload16(Bb + goff[it] + k0, dst + 16384 + loff[it]);
            }
        }
        const ushort_t* As = (const ushort_t*)(smem + cur * BUFB);
        const ushort_t* Bs = (const ushort_t*)(smem + cur * BUFB + 16384);
        #pragma unroll
        for (int kk = 0; kk < 2; ++kk) {
            bf16x8 af[4], bfr[4];
            #pragma unroll
            for (int mi = 0; mi < 4; ++mi)
                af[mi] = *(const bf16x8*)&As[(wr*64 + mi*16 + fr)*64
                                             + ((kk*32 + fs*8) ^ sw)];
            #pragma unroll
            for (int ni = 0; ni < 4; ++ni)
                bfr[ni] = *(const bf16x8*)&Bs[(wc*64 + ni*16 + fr)*64
                                              + ((kk*32 + fs*8) ^ sw)];
            #pragma unroll
            for (int mi = 0; mi < 4; ++mi)
                #pragma unroll
                for (int ni = 0; ni < 4; ++ni)
                    acc[mi][ni] = __builtin_amdgcn_mfma_f32_16x16x32_bf16(
                        af[mi], bfr[ni], acc[mi][ni], 0, 0, 0);
        }
        __syncthreads();   // implicit vmcnt(0)+lgkmcnt(0): next buf ready, cur free
        cur ^= 1;
    }

    if (MODE == 4) {
        const int which = by / 6;                  // 0=Q,1=K,2=V (block-uniform)
        const int nb = (by % 6) * 128;             // hcol base
        if (which < 2) {
            ushort_t* dst = outB + (size_t)which * OUT_ELEMS;
            const float sc = (which == 0) ? scale : 1.f;
            #pragma unroll
            for (int mi = 0; mi < 4; ++mi) {
                #pragma unroll
                for (int ni = 0; ni < 4; ++ni) {
                    const int hcol = nb + wc*64 + ni*16 + fr;
                    const float bv = bias[which*768 + hcol];
                    const int hh = hcol >> 6, d = hcol & 63;
                    #pragma unroll
                    for (int j = 0; j < 4; ++j) {
                        const int m = bm + wr*64 + mi*16 + fs*4 + j;
                        float v = (acc[mi][ni][j] + bv) * sc;
                        size_t addr = (size_t)hh * HSTRIDE
                                    + (size_t)(m & 511) * 8192 + (m >> 9) * 64 + d;
                        dst[addr] = f2bf(v);
                    }
                }
            }
        } else {
            // V: transpose through LDS, coalesced stores to Vt[h][rd][j]
            ushort_t* Ts = (ushort_t*)smem;        // [128][130] = 33280B < 64KB
            __syncthreads();
            #pragma unroll
            for (int mi = 0; mi < 4; ++mi) {
                #pragma unroll
                for (int ni = 0; ni < 4; ++ni) {
                    const int nl = wc*64 + ni*16 + fr;
                    const float bv = bias[1536 + nb + nl];
                    #pragma unroll
                    for (int j = 0; j < 4; ++j) {
                        const int ml = wr*64 + mi*16 + fs*4 + j;
                        Ts[nl*130 + ml] = f2bf(acc[mi][ni][j] + bv);
                    }
                }
            }
            __syncthreads();
            ushort_t* dst = outB + 2 * OUT_ELEMS;
            const int base_h = nb >> 6;
            const int rblk = bm >> 9, jb = bm & 511;
            #pragma unroll
            for (int it = 0; it < 8; ++it) {
                const int idx = it * 256 + tid;
                const int row = idx >> 4, col8 = (idx & 15) * 8;
                const int hh = base_h + (row >> 6), d = row & 63;
                uint4 wv;
                wv.x = *(const uint*)&Ts[row*130 + col8];
                wv.y = *(const uint*)&Ts[row*130 + col8 + 2];
                wv.z = *(const uint*)&Ts[row*130 + col8 + 4];
                wv.w = *(const uint*)&Ts[row*130 + col8 + 6];
                size_t addr = (size_t)hh * HSTRIDE
                            + (size_t)(rblk*64 + d) * CDIM + jb + col8;
                *(uint4*)&dst[addr] = wv;
            }
        }
        return;
    }

    #pragma unroll
    for (int mi = 0; mi < 4; ++mi) {
        #pragma unroll
        for (int ni = 0; ni < 4; ++ni) {
            const int n = bn + wc*64 + ni*16 + fr;
            float bv = (MODE == 1) ? bias[n] : 0.f;
            #pragma unroll
            for (int j = 0; j < 4; ++j) {
                const int m = bm + wr*64 + mi*16 + fs*4 + j;
                float v = acc[mi][ni][j];
                if (MODE == 1) {
                    outF[(size_t)m * N + n] = v + bv;
                } else if (MODE == 2) {
                    outF[(size_t)plane * (CDIM*CDIM) + (size_t)m * CDIM + n] = v;
                } else { // MODE 3
                    size_t addr = ((size_t)(n >> 6) * CDIM + m) * EDIM
                                + h * DDIM + (n & 63);
                    outB[addr] = f2bf(v);
                }
            }
        }
    }
}

// ============================================================================
// softmax over 512 cols for H*C rows; sums 4 split-K partials first.
// fp32 probs -> attn (d_out), bf16 copy -> Pb.
// ============================================================================
__global__ __launch_bounds__(256)
void softmax_reduce(const float* __restrict__ part, float* __restrict__ attn,
                    ushort_t* __restrict__ Pb) {
    const int row = blockIdx.x;              // h*512 + c
    const int h = row >> 9, c = row & 511;
    const int tid = threadIdx.x;
    const int lane = tid & 63, wid = tid >> 6;
    __shared__ float red[8];

    float v0 = 0.f, v1 = 0.f;
    #pragma unroll
    for (int s = 0; s < 4; ++s) {
        const float* p = part + ((size_t)(h*4 + s) * (CDIM*CDIM)) + (size_t)c * CDIM;
        v0 += p[tid];
        v1 += p[tid + 256];
    }
    float m = fmaxf(v0, v1);
    #pragma unroll
    for (int off = 32; off > 0; off >>= 1) m = fmaxf(m, __shfl_down(m, off));
    if (lane == 0) red[wid] = m;
    __syncthreads();
    if (tid == 0) red[4] = fmaxf(fmaxf(red[0], red[1]), fmaxf(red[2], red[3]));
    __syncthreads();
    const float M = red[4];

    float e0 = expf(v0 - M), e1 = expf(v1 - M);
    float s = e0 + e1;
    #pragma unroll
    for (int off = 32; off > 0; off >>= 1) s += __shfl_down(s, off);
    __syncthreads();
    if (lane == 0) red[wid] = s;
    __syncthreads();
    if (tid == 0) red[5] = red[0] + red[1] + red[2] + red[3];
    __syncthreads();
    const float inv = 1.f / red[5];
    float o0 = e0 * inv, o1 = e1 * inv;
    float* pout = attn + (size_t)row * CDIM;
    ushort_t* pb = Pb + (size_t)row * CDIM;
    pout[tid] = o0;        pout[tid + 256] = o1;
    pb[tid]   = f2bf(o0);  pb[tid + 256]   = f2bf(o1);
}

// ============================================================================
extern "C" void kernel_launch(void* const* d_in, const int* in_sizes, int n_in,
                              void* d_out, int out_size, void* d_ws, size_t ws_size,
                              hipStream_t stream) {
    const float* x  = (const float*)d_in[0];
    const float* Wq = (const float*)d_in[1];
    const float* bq = (const float*)d_in[2];
    const float* Wk = (const float*)d_in[3];
    const float* bk = (const float*)d_in[4];
    const float* Wv = (const float*)d_in[5];
    const float* bv = (const float*)d_in[6];
    const float* Wo = (const float*)d_in[7];
    const float* bo = (const float*)d_in[8];

    float* out   = (float*)d_out;
    float* attnp = out + OUT_ELEMS;            // attn_probs fp32 output region

    // workspace layout (ushort units)
    ushort_t* ws   = (ushort_t*)d_ws;
    ushort_t* xb   = ws;                                   // 100 MB; reused as ctxb
    ushort_t* Wqkv = xb + OUT_ELEMS;                       // [2304][768]
    ushort_t* Wto  = Wqkv + 3*WELEMS;
    float*    bqkv = (float*)(Wto + WELEMS);               // 2304 fp32
    ushort_t* Qp   = Wto + WELEMS + 4608;                  // [12][512][8192]
    ushort_t* Kp   = Qp + OUT_ELEMS;                       // contiguous after Qp
    ushort_t* Vt   = Kp + OUT_ELEMS;                       // [12][8192][512]
    ushort_t* Pb   = Vt + OUT_ELEMS;                       // [12][512][512]
    float*    part = (float*)(Pb + (size_t)HDIM*CDIM*CDIM); // 48 planes fp32
    ushort_t* ctxb = xb;                                   // reuse after QKV GEMM

    const float scaling = 0.011048543456039806f;  // 64^-0.5 / sqrt(128)

    // 1. casts / weight transposes / bias concat
    cast_x<<<MDIM*EDIM/(256*8), 256, 0, stream>>>(x, xb);
    dim3 wt(EDIM/64, EDIM/64);
    transpose_cast_w<<<wt, 256, 0, stream>>>(Wq, Wqkv);
    transpose_cast_w<<<wt, 256, 0, stream>>>(Wk, Wqkv + WELEMS);
    transpose_cast_w<<<wt, 256, 0, stream>>>(Wv, Wqkv + 2*WELEMS);
    transpose_cast_w<<<wt, 256, 0, stream>>>(Wo, Wto);
    concat_bias<<<9, 256, 0, stream>>>(bq, bk, bv, bqkv);

    // 2. fused QKV projection (Q,K per-head; V direct-transposed)
    gemm_bt<MDIM, 2304, EDIM, EDIM, 4, 9216><<<9216, 256, 0, stream>>>(
        xb, Wqkv, bqkv, scaling, nullptr, Qp, 0, 0);

    // 3. attn logits, split-K=4: per head 512x512, K-chunks of 2048
    gemm_bt<CDIM, CDIM, 2048, 8192, 2, 768><<<768, 256, 0, stream>>>(
        Qp, Kp, nullptr, 1.f, part, nullptr, HSTRIDE, HSTRIDE);

    // 4. softmax (+4-way partial reduce), fp32 out + bf16 copy
    softmax_reduce<<<HDIM*CDIM, 256, 0, stream>>>(part, attnp, Pb);

    // 5. context: per head 512x8192xK512 -> bf16 token-major
    gemm_bt<CDIM, 8192, CDIM, CDIM, 3, 3072><<<3072, 256, 0, stream>>>(
        Pb, Vt, nullptr, 1.f, nullptr, ctxb, (size_t)CDIM*CDIM, HSTRIDE);

    // 6. output projection (fp32 + bias)
    gemm_bt<MDIM, EDIM, EDIM, EDIM, 1, 3072><<<3072, 256, 0, stream>>>(
        ctxb, Wto, bo, 1.f, out, nullptr, 0, 0);
}

// Round 7
// 608.667 us; speedup vs baseline: 1.4100x; 1.1619x over previous
//
#include <hip/hip_runtime.h>
#include <math.h>

#define RDIM 128
#define CDIM 512
#define EDIM 768
#define HDIM 12
#define DDIM 64
#define MDIM (RDIM*CDIM)                  // 65536 tokens
#define OUT_ELEMS ((size_t)MDIM*EDIM)     // 50331648
#define HSTRIDE ((size_t)CDIM*RDIM*DDIM)  // 4194304 elems per head (512*8192)
#define WELEMS (EDIM*EDIM)                // 589824

typedef unsigned short ushort_t;
typedef __attribute__((ext_vector_type(8))) short bf16x8;
typedef __attribute__((ext_vector_type(8))) unsigned short u16x8;
typedef __attribute__((ext_vector_type(4))) float f32x4;

__device__ __forceinline__ ushort_t f2bf(float f) {
    unsigned u = __float_as_uint(f);
    unsigned r = u + 0x7fffu + ((u >> 16) & 1u);   // round-to-nearest-even
    return (ushort_t)(r >> 16);
}

__device__ __forceinline__ void gload16(const void* g, void* l) {
    __builtin_amdgcn_global_load_lds(
        (const __attribute__((address_space(1))) unsigned int*)g,
        (__attribute__((address_space(3))) unsigned int*)l, 16, 0, 0);
}

// ============================================================================
// cast x (fp32) -> bf16, 8 elems/thread
// ============================================================================
__global__ __launch_bounds__(256)
void cast_x(const float* __restrict__ x, ushort_t* __restrict__ xb) {
    size_t i = ((size_t)blockIdx.x * 256 + threadIdx.x) * 8;
    float4 a = *(const float4*)&x[i];
    float4 b = *(const float4*)&x[i + 4];
    u16x8 o;
    o[0]=f2bf(a.x); o[1]=f2bf(a.y); o[2]=f2bf(a.z); o[3]=f2bf(a.w);
    o[4]=f2bf(b.x); o[5]=f2bf(b.y); o[6]=f2bf(b.z); o[7]=f2bf(b.w);
    *(u16x8*)&xb[i] = o;
}

// ============================================================================
// W[k][n] fp32 -> Wt[n][k] bf16   (768x768)
// ============================================================================
__global__ __launch_bounds__(256)
void transpose_cast_w(const float* __restrict__ W, ushort_t* __restrict__ Wt) {
    __shared__ ushort_t t[64][66];
    const int k0 = blockIdx.x * 64, n0 = blockIdx.y * 64;
    const int tx = threadIdx.x & 15, ty = threadIdx.x >> 4;
    #pragma unroll
    for (int rep = 0; rep < 4; ++rep) {
        int k = ty + rep * 16;
        float4 v = *(const float4*)&W[(size_t)(k0 + k) * EDIM + n0 + tx*4];
        t[k][tx*4+0] = f2bf(v.x); t[k][tx*4+1] = f2bf(v.y);
        t[k][tx*4+2] = f2bf(v.z); t[k][tx*4+3] = f2bf(v.w);
    }
    __syncthreads();
    #pragma unroll
    for (int rep = 0; rep < 4; ++rep) {
        int n = ty + rep * 16;
        ushort4 o = { t[tx*4+0][n], t[tx*4+1][n], t[tx*4+2][n], t[tx*4+3][n] };
        *(ushort4*)&Wt[(size_t)(n0 + n) * EDIM + k0 + tx*4] = o;
    }
}

// ============================================================================
// concat biases -> bqkv[2304] fp32
// ============================================================================
__global__ __launch_bounds__(256)
void concat_bias(const float* __restrict__ bq, const float* __restrict__ bk,
                 const float* __restrict__ bv, float* __restrict__ bqkv) {
    int i = blockIdx.x * 256 + threadIdx.x;
    if (i < 768)        bqkv[i] = bq[i];
    else if (i < 1536)  bqkv[i] = bk[i - 768];
    else if (i < 2304)  bqkv[i] = bv[i - 1536];
}

// ============================================================================
// 8-phase 256x256 BT-GEMM (m201-style), BK=64, 512 thr = 8 waves.
// Per wave: 256(m) x 32(n) output = acc[16 m-frags][2 n-frags].
// LDS 128 KiB = per operand 4 half-tile slots (16 KB = 128 rows x 64 cols),
// slot(t,h) = (t&1)*2+h. T2 swizzle: linear LDS dest, inverse-swizzled global
// source (seg^row&7), XOR on ds_read col. K-tile t = 4 phases; phase p
// consumes A rows 64p..64p+63 (+ all B in P0, held in regs). Stage schedule
// (issued in phase X, AFTER barrier-2 of the slot's last-consuming phase):
//   P0: A1(t+1)   P1: B0(t+2)   P2: B1(t+2)   P3: A0(t+2)
// Counted waits (per-thread, 2 loads/half): P1: vmcnt(10) ensures A1(t);
// P3: vmcnt(8) ensures A0/B0/B1(t+1). Tail (last 2 tiles): vmcnt(0) once.
// MODE 1: out proj fp32+bias, w = mt*3+nt                  (NWG=768)
// MODE 2: split-K4 logits fp32, w = plane*4 + mt*2+nt      (NWG=192)
// MODE 3: context bf16 token-major, w = h*64 + mt*32 + nt  (NWG=768)
// MODE 4: fused QKV, w = mt*9 + ntile                      (NWG=2304)
// ============================================================================
#define SBAR do { __builtin_amdgcn_sched_barrier(0); \
                  __builtin_amdgcn_s_barrier(); \
                  __builtin_amdgcn_sched_barrier(0); } while(0)
#define LGKM0 do { asm volatile("s_waitcnt lgkmcnt(0)" ::: "memory"); \
                   __builtin_amdgcn_sched_barrier(0); } while(0)
#define VMCNT(n_) asm volatile("s_waitcnt vmcnt(" #n_ ")" ::: "memory")

template<int M, int N, int K, int LDK, int MODE, int NWG>
__global__ __launch_bounds__(512, 2)
void gemm8(const ushort_t* __restrict__ A, const ushort_t* __restrict__ B,
           const float* __restrict__ bias, float scale,
           float* __restrict__ outF, ushort_t* __restrict__ outB,
           size_t sAh, size_t sBh) {
    __shared__ __align__(16) char smem[131072];
    constexpr int NT = K / 64;

    const int tid = threadIdx.x;
    const int lane = tid & 63, wid = tid >> 6;
    const int fr = lane & 15, fs = lane >> 4;
    const int sw = (fr & 7) << 3;

    const int bid = blockIdx.x;
    const int w = (bid & 7) * (NWG / 8) + (bid >> 3);
    int bm, bn, h = 0, ksub = 0, plane = 0, ntile = 0;
    if (MODE == 4)      { ntile = w % 9; bm = (w / 9) * 256; bn = ntile * 256; }
    else if (MODE == 2) { plane = w >> 2; h = plane >> 2; ksub = plane & 3;
                          bm = ((w >> 1) & 1) * 256; bn = (w & 1) * 256; }
    else if (MODE == 3) { h = w >> 6; bm = ((w >> 5) & 1) * 256; bn = (w & 31) * 256; }
    else                { bm = (w / 3) * 256; bn = (w % 3) * 256; }

    const ushort_t* Ab = A + (MODE == 2 || MODE == 3 ? (size_t)h * sAh : 0)
                       + (MODE == 2 ? (size_t)ksub * 2048 : 0) + (size_t)bm * LDK;
    const ushort_t* Bb = B + (MODE == 2 || MODE == 3 ? (size_t)h * sBh : 0)
                       + (MODE == 2 ? (size_t)ksub * 2048 : 0) + (size_t)bn * LDK;

    // staging: half-tile = 128 rows x 64 cols; 2 gload16/thread
    const int r0 = tid >> 3, s0 = tid & 7;
    const size_t gO0 = (size_t)r0 * LDK + ((s0 ^ (r0 & 7)) * 8);
    const size_t gO1 = gO0 + (size_t)64 * LDK;      // (row+64)&7 == row&7
    const int l0 = tid * 16, l1 = tid * 16 + 8192;

#define STAGE_A(t_, h_) do { \
    char* d_ = smem + ((((t_) & 1) * 2 + (h_)) * 16384); \
    const ushort_t* s_ = Ab + (size_t)((h_) * 128) * LDK + (t_) * 64; \
    gload16(s_ + gO0, d_ + l0); gload16(s_ + gO1, d_ + l1); } while(0)
#define STAGE_B(t_, h_) do { \
    char* d_ = smem + 65536 + ((((t_) & 1) * 2 + (h_)) * 16384); \
    const ushort_t* s_ = Bb + (size_t)((h_) * 128) * LDK + (t_) * 64; \
    gload16(s_ + gO0, d_ + l0); gload16(s_ + gO1, d_ + l1); } while(0)

    f32x4 acc[16][2];
    #pragma unroll
    for (int i = 0; i < 16; ++i)
        #pragma unroll
        for (int j = 0; j < 2; ++j) acc[i][j] = (f32x4){0.f, 0.f, 0.f, 0.f};
    bf16x8 a_[4][2], b_[2][2];

#define DSREADS(t_, p_, LOADB_) do { \
    const ushort_t* As_ = (const ushort_t*)(smem + ((((t_) & 1) * 2 + ((p_) >> 1)) * 16384)); \
    _Pragma("unroll") for (int f = 0; f < 4; ++f) \
      _Pragma("unroll") for (int kk = 0; kk < 2; ++kk) \
        a_[f][kk] = *(const bf16x8*)&As_[(((p_) & 1) * 64 + f * 16 + fr) * 64 \
                                          + ((kk * 32 + fs * 8) ^ sw)]; \
    if (LOADB_) { \
      const ushort_t* Bs_ = (const ushort_t*)(smem + 65536 + ((((t_) & 1) * 2 + (wid >> 2)) * 16384)); \
      _Pragma("unroll") for (int nf = 0; nf < 2; ++nf) \
        _Pragma("unroll") for (int kk = 0; kk < 2; ++kk) \
          b_[nf][kk] = *(const bf16x8*)&Bs_[((wid & 3) * 32 + nf * 16 + fr) * 64 \
                                             + ((kk * 32 + fs * 8) ^ sw)]; } } while(0)

#define MFMA16(p_) do { \
    __builtin_amdgcn_s_setprio(1); \
    _Pragma("unroll") for (int f = 0; f < 4; ++f) \
      _Pragma("unroll") for (int nf = 0; nf < 2; ++nf) \
        _Pragma("unroll") for (int kk = 0; kk < 2; ++kk) \
          acc[(p_) * 4 + f][nf] = __builtin_amdgcn_mfma_f32_16x16x32_bf16( \
              a_[f][kk], b_[nf][kk], acc[(p_) * 4 + f][nf], 0, 0, 0); \
    __builtin_amdgcn_s_setprio(0); } while(0)

    // ---- prologue: 7 half-tiles, order-pinned for vmcnt accounting ----
    STAGE_B(0, 0); __builtin_amdgcn_sched_barrier(0);
    STAGE_B(0, 1); __builtin_amdgcn_sched_barrier(0);
    STAGE_A(0, 0); __builtin_amdgcn_sched_barrier(0);
    STAGE_A(0, 1); __builtin_amdgcn_sched_barrier(0);
    STAGE_B(1, 0); __builtin_amdgcn_sched_barrier(0);
    STAGE_B(1, 1); __builtin_amdgcn_sched_barrier(0);
    STAGE_A(1, 0); __builtin_amdgcn_sched_barrier(0);
    VMCNT(8);                       // B0(0),B1(0),A0(0) landed
    SBAR;

    // ---- main loop: tiles 0 .. NT-3, steady 8-phase (2 tiles per 8 phases) ----
    for (int t = 0; t < NT - 2; ++t) {
        // P0: consumes A rows 0-63 + all B of tile t
        DSREADS(t, 0, 1);
        STAGE_A(t + 1, 1);
        SBAR; LGKM0; MFMA16(0); SBAR;
        // P1
        DSREADS(t, 1, 0);
        STAGE_B(t + 2, 0);
        VMCNT(10);                  // A1(t) landed (needed by P2)
        SBAR; LGKM0; MFMA16(1); SBAR;
        // P2
        DSREADS(t, 2, 0);
        STAGE_B(t + 2, 1);
        SBAR; LGKM0; MFMA16(2); SBAR;
        // P3
        DSREADS(t, 3, 0);
        STAGE_A(t + 2, 0);
        VMCNT(8);                   // A0/B0/B1(t+1) landed
        SBAR; LGKM0; MFMA16(3); SBAR;
    }

    // ---- tail: stage final half, drain once, compute tiles NT-2, NT-1 ----
    STAGE_A(NT - 1, 1);             // A1(NT-1); slot last read in P2/P3(NT-3)
    VMCNT(0);
    SBAR;
    {
        constexpr int t0 = NT - 2;
        #pragma unroll
        for (int p = 0; p < 4; ++p) {
            DSREADS(t0, p, p == 0);
            SBAR; LGKM0; MFMA16(p); SBAR;
        }
        constexpr int t1 = NT - 1;
        #pragma unroll
        for (int p = 0; p < 4; ++p) {
            DSREADS(t1, p, p == 0);
            SBAR; LGKM0; MFMA16(p); SBAR;
        }
    }

    // ---- epilogues ----
    if (MODE == 4) {
        const int which = ntile / 3;               // 0=Q,1=K,2=V
        const int hcb = (ntile % 3) * 256;         // hcol base
        if (which < 2) {
            ushort_t* dst = outB + (size_t)which * OUT_ELEMS;
            const float sc = (which == 0) ? scale : 1.f;
            #pragma unroll
            for (int mf = 0; mf < 16; ++mf) {
                #pragma unroll
                for (int nf = 0; nf < 2; ++nf) {
                    const int hcol = hcb + wid*32 + nf*16 + fr;
                    const float bv = bias[which*768 + hcol];
                    const int hh = hcol >> 6, d = hcol & 63;
                    #pragma unroll
                    for (int j = 0; j < 4; ++j) {
                        const int m = bm + mf*16 + fs*4 + j;
                        float v = (acc[mf][nf][j] + bv) * sc;
                        size_t addr = (size_t)hh * HSTRIDE
                                    + (size_t)(m & 511) * 8192 + (m >> 9) * 64 + d;
                        dst[addr] = f2bf(v);
                    }
                }
            }
        } else {
            // V: transpose via LDS (2 passes of 128 n-rows), coalesced to Vt
            ushort_t* Ts = (ushort_t*)smem;        // [128][258] = 66048 B
            ushort_t* dst = outB + 2 * OUT_ELEMS;
            const int rblk = bm >> 9, jb = bm & 511;
            __syncthreads();
            #pragma unroll
            for (int q = 0; q < 2; ++q) {
                if ((wid >> 2) == q) {
                    #pragma unroll
                    for (int mf = 0; mf < 16; ++mf) {
                        #pragma unroll
                        for (int nf = 0; nf < 2; ++nf) {
                            const int nl = wid*32 + nf*16 + fr;
                            const float bv = bias[1536 + hcb + nl];
                            #pragma unroll
                            for (int j = 0; j < 4; ++j)
                                Ts[(nl & 127)*258 + mf*16 + fs*4 + j] =
                                    f2bf(acc[mf][nf][j] + bv);
                        }
                    }
                }
                __syncthreads();
                #pragma unroll
                for (int it = 0; it < 8; ++it) {
                    const int idx = it * 512 + tid;
                    const int row = idx >> 5, c8 = (idx & 31) * 8;
                    const int nl = q*128 + row;
                    const int hh = (hcb + nl) >> 6, d = nl & 63;
                    uint4 wv;
                    wv.x = *(const uint*)&Ts[row*258 + c8];
                    wv.y = *(const uint*)&Ts[row*258 + c8 + 2];
                    wv.z = *(const uint*)&Ts[row*258 + c8 + 4];
                    wv.w = *(const uint*)&Ts[row*258 + c8 + 6];
                    size_t addr = (size_t)hh * HSTRIDE
                                + (size_t)(rblk*64 + d) * CDIM + jb + c8;
                    *(uint4*)&dst[addr] = wv;
                }
                __syncthreads();
            }
        }
        return;
    }

    #pragma unroll
    for (int mf = 0; mf < 16; ++mf) {
        #pragma unroll
        for (int nf = 0; nf < 2; ++nf) {
            const int n = bn + wid*32 + nf*16 + fr;
            float bv = (MODE == 1) ? bias[n] : 0.f;
            #pragma unroll
            for (int j = 0; j < 4; ++j) {
                const int m = bm + mf*16 + fs*4 + j;
                float v = acc[mf][nf][j];
                if (MODE == 1) {
                    outF[(size_t)m * N + n] = v + bv;
                } else if (MODE == 2) {
                    outF[(size_t)plane * (CDIM*CDIM) + (size_t)m * CDIM + n] = v;
                } else { // MODE 3
                    size_t addr = ((size_t)(n >> 6) * CDIM + m) * EDIM
                                + h * DDIM + (n & 63);
                    outB[addr] = f2bf(v);
                }
            }
        }
    }
}

// ============================================================================
// softmax over 512 cols for H*C rows; sums 4 split-K partials first.
// fp32 probs -> attn (d_out), bf16 copy -> Pb.
// ============================================================================
__global__ __launch_bounds__(256)
void softmax_reduce(const float* __restrict__ part, float* __restrict__ attn,
                    ushort_t* __restrict__ Pb) {
    const int row = blockIdx.x;              // h*512 + c
    const int h = row >> 9, c = row & 511;
    const int tid = threadIdx.x;
    const int lane = tid & 63, wid = tid >> 6;
    __shared__ float red[8];

    float v0 = 0.f, v1 = 0.f;
    #pragma unroll
    for (int s = 0; s < 4; ++s) {
        const float* p = part + ((size_t)(h*4 + s) * (CDIM*CDIM)) + (size_t)c * CDIM;
        v0 += p[tid];
        v1 += p[tid + 256];
    }
    float m = fmaxf(v0, v1);
    #pragma unroll
    for (int off = 32; off > 0; off >>= 1) m = fmaxf(m, __shfl_down(m, off));
    if (lane == 0) red[wid] = m;
    __syncthreads();
    if (tid == 0) red[4] = fmaxf(fmaxf(red[0], red[1]), fmaxf(red[2], red[3]));
    __syncthreads();
    const float M = red[4];

    float e0 = expf(v0 - M), e1 = expf(v1 - M);
    float s = e0 + e1;
    #pragma unroll
    for (int off = 32; off > 0; off >>= 1) s += __shfl_down(s, off);
    __syncthreads();
    if (lane == 0) red[wid] = s;
    __syncthreads();
    if (tid == 0) red[5] = red[0] + red[1] + red[2] + red[3];
    __syncthreads();
    const float inv = 1.f / red[5];
    float o0 = e0 * inv, o1 = e1 * inv;
    float* pout = attn + (size_t)row * CDIM;
    ushort_t* pb = Pb + (size_t)row * CDIM;
    pout[tid] = o0;        pout[tid + 256] = o1;
    pb[tid]   = f2bf(o0);  pb[tid + 256]   = f2bf(o1);
}

// ============================================================================
extern "C" void kernel_launch(void* const* d_in, const int* in_sizes, int n_in,
                              void* d_out, int out_size, void* d_ws, size_t ws_size,
                              hipStream_t stream) {
    const float* x  = (const float*)d_in[0];
    const float* Wq = (const float*)d_in[1];
    const float* bq = (const float*)d_in[2];
    const float* Wk = (const float*)d_in[3];
    const float* bk = (const float*)d_in[4];
    const float* Wv = (const float*)d_in[5];
    const float* bv = (const float*)d_in[6];
    const float* Wo = (const float*)d_in[7];
    const float* bo = (const float*)d_in[8];

    float* out   = (float*)d_out;
    float* attnp = out + OUT_ELEMS;            // attn_probs fp32 output region

    // workspace layout (ushort units)
    ushort_t* ws   = (ushort_t*)d_ws;
    ushort_t* xb   = ws;                                   // 100 MB; reused as ctxb
    ushort_t* Wqkv = xb + OUT_ELEMS;                       // [2304][768]
    ushort_t* Wto  = Wqkv + 3*WELEMS;
    float*    bqkv = (float*)(Wto + WELEMS);               // 2304 fp32
    ushort_t* Qp   = Wto + WELEMS + 4608;                  // [12][512][8192]
    ushort_t* Kp   = Qp + OUT_ELEMS;                       // contiguous after Qp
    ushort_t* Vt   = Kp + OUT_ELEMS;                       // [12][8192][512]
    ushort_t* Pb   = Vt + OUT_ELEMS;                       // [12][512][512]
    float*    part = (float*)(Pb + (size_t)HDIM*CDIM*CDIM); // 48 planes fp32
    ushort_t* ctxb = xb;                                   // reuse after QKV GEMM

    const float scaling = 0.011048543456039806f;  // 64^-0.5 / sqrt(128)

    // 1. casts / weight transposes / bias concat
    cast_x<<<MDIM*EDIM/(256*8), 256, 0, stream>>>(x, xb);
    dim3 wt(EDIM/64, EDIM/64);
    transpose_cast_w<<<wt, 256, 0, stream>>>(Wq, Wqkv);
    transpose_cast_w<<<wt, 256, 0, stream>>>(Wk, Wqkv + WELEMS);
    transpose_cast_w<<<wt, 256, 0, stream>>>(Wv, Wqkv + 2*WELEMS);
    transpose_cast_w<<<wt, 256, 0, stream>>>(Wo, Wto);
    concat_bias<<<9, 256, 0, stream>>>(bq, bk, bv, bqkv);

    // 2. fused QKV projection (Q,K per-head; V direct-transposed)
    gemm8<MDIM, 2304, EDIM, EDIM, 4, 2304><<<2304, 512, 0, stream>>>(
        xb, Wqkv, bqkv, scaling, nullptr, Qp, 0, 0);

    // 3. attn logits, split-K=4: per head 512x512, K-chunks of 2048
    gemm8<CDIM, CDIM, 2048, 8192, 2, 192><<<192, 512, 0, stream>>>(
        Qp, Kp, nullptr, 1.f, part, nullptr, HSTRIDE, HSTRIDE);

    // 4. softmax (+4-way partial reduce), fp32 out + bf16 copy
    softmax_reduce<<<HDIM*CDIM, 256, 0, stream>>>(part, attnp, Pb);

    // 5. context: per head 512x8192xK512 -> bf16 token-major
    gemm8<CDIM, 8192, CDIM, CDIM, 3, 768><<<768, 512, 0, stream>>>(
        Pb, Vt, nullptr, 1.f, nullptr, ctxb, (size_t)CDIM*CDIM, HSTRIDE);

    // 6. output projection (fp32 + bias)
    gemm8<MDIM, EDIM, EDIM, EDIM, 1, 768><<<768, 512, 0, stream>>>(
        ctxb, Wto, bo, 1.f, out, nullptr, 0, 0);
}

// Round 8
// 587.788 us; speedup vs baseline: 1.4601x; 1.0355x over previous
//
#include <hip/hip_runtime.h>
#include <math.h>

#define RDIM 128
#define CDIM 512
#define EDIM 768
#define HDIM 12
#define DDIM 64
#define MDIM (RDIM*CDIM)                  // 65536 tokens
#define OUT_ELEMS ((size_t)MDIM*EDIM)     // 50331648
#define HSTRIDE ((size_t)CDIM*RDIM*DDIM)  // 4194304 elems per head (512*8192)
#define WELEMS (EDIM*EDIM)                // 589824

typedef unsigned short ushort_t;
typedef __attribute__((ext_vector_type(8))) short bf16x8;
typedef __attribute__((ext_vector_type(8))) unsigned short u16x8;
typedef __attribute__((ext_vector_type(4))) float f32x4;

__device__ __forceinline__ ushort_t f2bf(float f) {
    unsigned u = __float_as_uint(f);
    unsigned r = u + 0x7fffu + ((u >> 16) & 1u);   // round-to-nearest-even
    return (ushort_t)(r >> 16);
}

__device__ __forceinline__ void gload16(const void* g, void* l) {
    __builtin_amdgcn_global_load_lds(
        (const __attribute__((address_space(1))) unsigned int*)g,
        (__attribute__((address_space(3))) unsigned int*)l, 16, 0, 0);
}

// ============================================================================
// cast x (fp32) -> bf16, 8 elems/thread
// ============================================================================
__global__ __launch_bounds__(256)
void cast_x(const float* __restrict__ x, ushort_t* __restrict__ xb) {
    size_t i = ((size_t)blockIdx.x * 256 + threadIdx.x) * 8;
    float4 a = *(const float4*)&x[i];
    float4 b = *(const float4*)&x[i + 4];
    u16x8 o;
    o[0]=f2bf(a.x); o[1]=f2bf(a.y); o[2]=f2bf(a.z); o[3]=f2bf(a.w);
    o[4]=f2bf(b.x); o[5]=f2bf(b.y); o[6]=f2bf(b.z); o[7]=f2bf(b.w);
    *(u16x8*)&xb[i] = o;
}

// ============================================================================
// W[k][n] fp32 -> Wt[n][k] bf16   (768x768)
// ============================================================================
__global__ __launch_bounds__(256)
void transpose_cast_w(const float* __restrict__ W, ushort_t* __restrict__ Wt) {
    __shared__ ushort_t t[64][66];
    const int k0 = blockIdx.x * 64, n0 = blockIdx.y * 64;
    const int tx = threadIdx.x & 15, ty = threadIdx.x >> 4;
    #pragma unroll
    for (int rep = 0; rep < 4; ++rep) {
        int k = ty + rep * 16;
        float4 v = *(const float4*)&W[(size_t)(k0 + k) * EDIM + n0 + tx*4];
        t[k][tx*4+0] = f2bf(v.x); t[k][tx*4+1] = f2bf(v.y);
        t[k][tx*4+2] = f2bf(v.z); t[k][tx*4+3] = f2bf(v.w);
    }
    __syncthreads();
    #pragma unroll
    for (int rep = 0; rep < 4; ++rep) {
        int n = ty + rep * 16;
        ushort4 o = { t[tx*4+0][n], t[tx*4+1][n], t[tx*4+2][n], t[tx*4+3][n] };
        *(ushort4*)&Wt[(size_t)(n0 + n) * EDIM + k0 + tx*4] = o;
    }
}

// ============================================================================
// concat biases -> bqkv[2304] fp32
// ============================================================================
__global__ __launch_bounds__(256)
void concat_bias(const float* __restrict__ bq, const float* __restrict__ bk,
                 const float* __restrict__ bv, float* __restrict__ bqkv) {
    int i = blockIdx.x * 256 + threadIdx.x;
    if (i < 768)        bqkv[i] = bq[i];
    else if (i < 1536)  bqkv[i] = bk[i - 768];
    else if (i < 2304)  bqkv[i] = bv[i - 1536];
}

// ============================================================================
// 8-phase 256x256 BT-GEMM, BK=64, 512 thr = 8 waves in a 2M x 4N grid:
// per-wave output 128m x 64n  -> acc[8 m-frags][4 n-frags].
// LDS-read per block per K-tile = 8 waves x 24KB = 192KB (balanced vs MFMA),
// vs 288KB of the previous 256x32 decomposition (the round-7 LDS-pipe wall).
// LDS: per operand 4 half-tile slots (16KB = 128 rows x 64 cols),
// slot(t,h)=(t&1)*2+h. Wave reads A-slot wr only (its 128 m-rows) and
// B-slot wc>>1 only. Phase plan per K-tile t (16 MFMA each):
//   P0: ds A(mq0) 8 + ds B all 8 -> MFMA(mq0,nq0)
//   P1: stage B0(t+2)            -> MFMA(mq0,nq1)
//   P2: ds A(mq1) 8, stage B1(t+2) -> MFMA(mq1,nq0)
//   P3: stage A0+A1(t+2)         -> MFMA(mq1,nq1); vmcnt(8)
// Ledger: B(t) free after P0-bar, A(t) free after P2-bar; data for t+1 was
// staged during t-1 -> single vmcnt(8) at P3 guarantees it. One barrier/phase.
// T2 swizzle: linear LDS dest, source seg^=(row&7), read col ^sw.
// T1 bijective XCD swizzle on flat grid, reuse dim innermost.
// MODE 1: out proj fp32+bias, w = mt*3+nt                  (NWG=768)
// MODE 2: split-K4 logits fp32, w = plane*4 + mt*2+nt      (NWG=192)
// MODE 3: context bf16 token-major, w = h*64 + mt*32 + nt  (NWG=768)
// MODE 4: fused QKV, w = mt*9 + ntile                      (NWG=2304)
// ============================================================================
#define SBAR do { __builtin_amdgcn_sched_barrier(0); \
                  __builtin_amdgcn_s_barrier(); \
                  __builtin_amdgcn_sched_barrier(0); } while(0)
#define LGKM0 do { asm volatile("s_waitcnt lgkmcnt(0)" ::: "memory"); \
                   __builtin_amdgcn_sched_barrier(0); } while(0)
#define VMCNT(n_) asm volatile("s_waitcnt vmcnt(" #n_ ")" ::: "memory")

template<int M, int N, int K, int LDK, int MODE, int NWG>
__global__ __launch_bounds__(512, 2)
void gemm8(const ushort_t* __restrict__ A, const ushort_t* __restrict__ B,
           const float* __restrict__ bias, float scale,
           float* __restrict__ outF, ushort_t* __restrict__ outB,
           size_t sAh, size_t sBh) {
    __shared__ __align__(16) char smem[131072];
    constexpr int NT = K / 64;

    const int tid = threadIdx.x;
    const int lane = tid & 63, wid = tid >> 6;
    const int wr = wid >> 2, wc = wid & 3;          // 2M x 4N wave grid
    const int fr = lane & 15, fs = lane >> 4;
    const int sw = (fr & 7) << 3;

    const int bid = blockIdx.x;
    const int w = (bid & 7) * (NWG / 8) + (bid >> 3);
    int bm, bn, h = 0, ksub = 0, plane = 0, ntile = 0;
    if (MODE == 4)      { ntile = w % 9; bm = (w / 9) * 256; bn = ntile * 256; }
    else if (MODE == 2) { plane = w >> 2; h = plane >> 2; ksub = plane & 3;
                          bm = ((w >> 1) & 1) * 256; bn = (w & 1) * 256; }
    else if (MODE == 3) { h = w >> 6; bm = ((w >> 5) & 1) * 256; bn = (w & 31) * 256; }
    else                { bm = (w / 3) * 256; bn = (w % 3) * 256; }

    const ushort_t* Ab = A + (MODE == 2 || MODE == 3 ? (size_t)h * sAh : 0)
                       + (MODE == 2 ? (size_t)ksub * 2048 : 0) + (size_t)bm * LDK;
    const ushort_t* Bb = B + (MODE == 2 || MODE == 3 ? (size_t)h * sBh : 0)
                       + (MODE == 2 ? (size_t)ksub * 2048 : 0) + (size_t)bn * LDK;

    // staging: half-tile = 128 rows x 64 cols; 2 gload16/thread
    const int r0 = tid >> 3, s0 = tid & 7;
    const size_t gO0 = (size_t)r0 * LDK + ((s0 ^ (r0 & 7)) * 8);
    const size_t gO1 = gO0 + (size_t)64 * LDK;      // (row+64)&7 == row&7
    const int l0 = tid * 16, l1 = tid * 16 + 8192;

#define STAGE_A(t_, h_) do { \
    char* d_ = smem + ((((t_) & 1) * 2 + (h_)) * 16384); \
    const ushort_t* s_ = Ab + (size_t)((h_) * 128) * LDK + (t_) * 64; \
    gload16(s_ + gO0, d_ + l0); gload16(s_ + gO1, d_ + l1); } while(0)
#define STAGE_B(t_, h_) do { \
    char* d_ = smem + 65536 + ((((t_) & 1) * 2 + (h_)) * 16384); \
    const ushort_t* s_ = Bb + (size_t)((h_) * 128) * LDK + (t_) * 64; \
    gload16(s_ + gO0, d_ + l0); gload16(s_ + gO1, d_ + l1); } while(0)

    f32x4 acc[8][4];
    #pragma unroll
    for (int i = 0; i < 8; ++i)
        #pragma unroll
        for (int j = 0; j < 4; ++j) acc[i][j] = (f32x4){0.f, 0.f, 0.f, 0.f};
    bf16x8 a_[4][2], bb_[4][2];

#define DSA(t_, mq_) do { \
    const ushort_t* As_ = (const ushort_t*)(smem + ((((t_) & 1) * 2 + wr) * 16384)); \
    _Pragma("unroll") for (int f = 0; f < 4; ++f) \
      _Pragma("unroll") for (int kk = 0; kk < 2; ++kk) \
        a_[f][kk] = *(const bf16x8*)&As_[((mq_) * 64 + f * 16 + fr) * 64 \
                                          + ((kk * 32 + fs * 8) ^ sw)]; } while(0)

#define DSB(t_) do { \
    const ushort_t* Bs_ = (const ushort_t*)(smem + 65536 + ((((t_) & 1) * 2 + (wc >> 1)) * 16384)); \
    _Pragma("unroll") for (int nf = 0; nf < 4; ++nf) \
      _Pragma("unroll") for (int kk = 0; kk < 2; ++kk) \
        bb_[nf][kk] = *(const bf16x8*)&Bs_[((wc & 1) * 64 + nf * 16 + fr) * 64 \
                                            + ((kk * 32 + fs * 8) ^ sw)]; } while(0)

#define MFMA8(mq_, nq_) do { \
    __builtin_amdgcn_s_setprio(1); \
    _Pragma("unroll") for (int f = 0; f < 4; ++f) \
      _Pragma("unroll") for (int nf2 = 0; nf2 < 2; ++nf2) \
        _Pragma("unroll") for (int kk = 0; kk < 2; ++kk) \
          acc[(mq_) * 4 + f][(nq_) * 2 + nf2] = __builtin_amdgcn_mfma_f32_16x16x32_bf16( \
              a_[f][kk], bb_[(nq_) * 2 + nf2][kk], acc[(mq_) * 4 + f][(nq_) * 2 + nf2], 0, 0, 0); \
    __builtin_amdgcn_s_setprio(0); } while(0)

    // ---- prologue: stage tiles 0 and 1 (16 loads/thread) ----
    STAGE_B(0, 0); __builtin_amdgcn_sched_barrier(0);
    STAGE_B(0, 1); __builtin_amdgcn_sched_barrier(0);
    STAGE_A(0, 0); __builtin_amdgcn_sched_barrier(0);
    STAGE_A(0, 1); __builtin_amdgcn_sched_barrier(0);
    STAGE_B(1, 0); __builtin_amdgcn_sched_barrier(0);
    STAGE_B(1, 1); __builtin_amdgcn_sched_barrier(0);
    STAGE_A(1, 0); __builtin_amdgcn_sched_barrier(0);
    STAGE_A(1, 1); __builtin_amdgcn_sched_barrier(0);
    VMCNT(8);                       // tile 0's 8 halves landed
    SBAR;

    // ---- main loop ----
    for (int t = 0; t < NT - 2; ++t) {
        // P0
        DSA(t, 0); DSB(t);
        LGKM0; MFMA8(0, 0); SBAR;
        // P1
        STAGE_B(t + 2, 0);
        MFMA8(0, 1); SBAR;
        // P2
        DSA(t, 1);
        STAGE_B(t + 2, 1);
        LGKM0; MFMA8(1, 0); SBAR;
        // P3
        STAGE_A(t + 2, 0); STAGE_A(t + 2, 1);
        MFMA8(1, 1);
        VMCNT(8);                   // tile t+1's data all landed
        SBAR;
    }

    // ---- tail: tiles NT-2, NT-1 (no staging) ----
    #pragma unroll
    for (int tt = 0; tt < 2; ++tt) {
        const int t = NT - 2 + tt;
        if (tt == 1) { VMCNT(0); SBAR; }
        DSA(t, 0); DSB(t);
        LGKM0; MFMA8(0, 0); SBAR;
        MFMA8(0, 1); SBAR;
        DSA(t, 1);
        LGKM0; MFMA8(1, 0); SBAR;
        MFMA8(1, 1); SBAR;
    }

    // ---- epilogues ----
    if (MODE == 4) {
        const int which = ntile / 3;               // 0=Q,1=K,2=V
        const int hcb = (ntile % 3) * 256;         // hcol base
        if (which < 2) {
            ushort_t* dst = outB + (size_t)which * OUT_ELEMS;
            const float sc = (which == 0) ? scale : 1.f;
            #pragma unroll
            for (int mf = 0; mf < 8; ++mf) {
                #pragma unroll
                for (int nf = 0; nf < 4; ++nf) {
                    const int hcol = hcb + wc*64 + nf*16 + fr;
                    const float bv = bias[which*768 + hcol];
                    const int hh = hcol >> 6, d = hcol & 63;
                    #pragma unroll
                    for (int j = 0; j < 4; ++j) {
                        const int m = bm + wr*128 + mf*16 + fs*4 + j;
                        float v = (acc[mf][nf][j] + bv) * sc;
                        size_t addr = (size_t)hh * HSTRIDE
                                    + (size_t)(m & 511) * 8192 + (m >> 9) * 64 + d;
                        dst[addr] = f2bf(v);
                    }
                }
            }
        } else {
            // V: transpose via LDS (2 passes of 128 n-rows), coalesced to Vt
            ushort_t* Ts = (ushort_t*)smem;        // [128][264] = 67.6 KB
            ushort_t* dst = outB + 2 * OUT_ELEMS;
            const int rblk = bm >> 9, jb = bm & 511;
            __syncthreads();
            #pragma unroll
            for (int q = 0; q < 2; ++q) {
                if ((wc >> 1) == q) {
                    #pragma unroll
                    for (int mf = 0; mf < 8; ++mf) {
                        #pragma unroll
                        for (int nf = 0; nf < 4; ++nf) {
                            const int nl = wc*64 + nf*16 + fr;
                            const float bv = bias[1536 + hcb + nl];
                            #pragma unroll
                            for (int j = 0; j < 4; ++j)
                                Ts[(nl & 127)*264 + wr*128 + mf*16 + fs*4 + j] =
                                    f2bf(acc[mf][nf][j] + bv);
                        }
                    }
                }
                __syncthreads();
                #pragma unroll
                for (int it = 0; it < 8; ++it) {
                    const int idx = it * 512 + tid;
                    const int row = idx >> 5, c8 = (idx & 31) * 8;
                    const int nl = q*128 + row;
                    const int hh = (hcb + nl) >> 6, d = nl & 63;
                    uint4 wv;
                    wv.x = *(const uint*)&Ts[row*264 + c8];
                    wv.y = *(const uint*)&Ts[row*264 + c8 + 2];
                    wv.z = *(const uint*)&Ts[row*264 + c8 + 4];
                    wv.w = *(const uint*)&Ts[row*264 + c8 + 6];
                    size_t addr = (size_t)hh * HSTRIDE
                                + (size_t)(rblk*64 + d) * CDIM + jb + c8;
                    *(uint4*)&dst[addr] = wv;
                }
                __syncthreads();
            }
        }
        return;
    }

    #pragma unroll
    for (int mf = 0; mf < 8; ++mf) {
        #pragma unroll
        for (int nf = 0; nf < 4; ++nf) {
            const int n = bn + wc*64 + nf*16 + fr;
            float bv = (MODE == 1) ? bias[n] : 0.f;
            #pragma unroll
            for (int j = 0; j < 4; ++j) {
                const int m = bm + wr*128 + mf*16 + fs*4 + j;
                float v = acc[mf][nf][j];
                if (MODE == 1) {
                    outF[(size_t)m * N + n] = v + bv;
                } else if (MODE == 2) {
                    outF[(size_t)plane * (CDIM*CDIM) + (size_t)m * CDIM + n] = v;
                } else { // MODE 3
                    size_t addr = ((size_t)(n >> 6) * CDIM + m) * EDIM
                                + h * DDIM + (n & 63);
                    outB[addr] = f2bf(v);
                }
            }
        }
    }
}

// ============================================================================
// softmax over 512 cols for H*C rows; sums 4 split-K partials first.
// fp32 probs -> attn (d_out), bf16 copy -> Pb.
// ============================================================================
__global__ __launch_bounds__(256)
void softmax_reduce(const float* __restrict__ part, float* __restrict__ attn,
                    ushort_t* __restrict__ Pb) {
    const int row = blockIdx.x;              // h*512 + c
    const int h = row >> 9, c = row & 511;
    const int tid = threadIdx.x;
    const int lane = tid & 63, wid = tid >> 6;
    __shared__ float red[8];

    float v0 = 0.f, v1 = 0.f;
    #pragma unroll
    for (int s = 0; s < 4; ++s) {
        const float* p = part + ((size_t)(h*4 + s) * (CDIM*CDIM)) + (size_t)c * CDIM;
        v0 += p[tid];
        v1 += p[tid + 256];
    }
    float m = fmaxf(v0, v1);
    #pragma unroll
    for (int off = 32; off > 0; off >>= 1) m = fmaxf(m, __shfl_down(m, off));
    if (lane == 0) red[wid] = m;
    __syncthreads();
    if (tid == 0) red[4] = fmaxf(fmaxf(red[0], red[1]), fmaxf(red[2], red[3]));
    __syncthreads();
    const float M = red[4];

    float e0 = expf(v0 - M), e1 = expf(v1 - M);
    float s = e0 + e1;
    #pragma unroll
    for (int off = 32; off > 0; off >>= 1) s += __shfl_down(s, off);
    __syncthreads();
    if (lane == 0) red[wid] = s;
    __syncthreads();
    if (tid == 0) red[5] = red[0] + red[1] + red[2] + red[3];
    __syncthreads();
    const float inv = 1.f / red[5];
    float o0 = e0 * inv, o1 = e1 * inv;
    float* pout = attn + (size_t)row * CDIM;
    ushort_t* pb = Pb + (size_t)row * CDIM;
    pout[tid] = o0;        pout[tid + 256] = o1;
    pb[tid]   = f2bf(o0);  pb[tid + 256]   = f2bf(o1);
}

// ============================================================================
extern "C" void kernel_launch(void* const* d_in, const int* in_sizes, int n_in,
                              void* d_out, int out_size, void* d_ws, size_t ws_size,
                              hipStream_t stream) {
    const float* x  = (const float*)d_in[0];
    const float* Wq = (const float*)d_in[1];
    const float* bq = (const float*)d_in[2];
    const float* Wk = (const float*)d_in[3];
    const float* bk = (const float*)d_in[4];
    const float* Wv = (const float*)d_in[5];
    const float* bv = (const float*)d_in[6];
    const float* Wo = (const float*)d_in[7];
    const float* bo = (const float*)d_in[8];

    float* out   = (float*)d_out;
    float* attnp = out + OUT_ELEMS;            // attn_probs fp32 output region

    // workspace layout (ushort units)
    ushort_t* ws   = (ushort_t*)d_ws;
    ushort_t* xb   = ws;                                   // 100 MB; reused as ctxb
    ushort_t* Wqkv = xb + OUT_ELEMS;                       // [2304][768]
    ushort_t* Wto  = Wqkv + 3*WELEMS;
    float*    bqkv = (float*)(Wto + WELEMS);               // 2304 fp32
    ushort_t* Qp   = Wto + WELEMS + 4608;                  // [12][512][8192]
    ushort_t* Kp   = Qp + OUT_ELEMS;                       // contiguous after Qp
    ushort_t* Vt   = Kp + OUT_ELEMS;                       // [12][8192][512]
    ushort_t* Pb   = Vt + OUT_ELEMS;                       // [12][512][512]
    float*    part = (float*)(Pb + (size_t)HDIM*CDIM*CDIM); // 48 planes fp32
    ushort_t* ctxb = xb;                                   // reuse after QKV GEMM

    const float scaling = 0.011048543456039806f;  // 64^-0.5 / sqrt(128)

    // 1. casts / weight transposes / bias concat
    cast_x<<<MDIM*EDIM/(256*8), 256, 0, stream>>>(x, xb);
    dim3 wt(EDIM/64, EDIM/64);
    transpose_cast_w<<<wt, 256, 0, stream>>>(Wq, Wqkv);
    transpose_cast_w<<<wt, 256, 0, stream>>>(Wk, Wqkv + WELEMS);
    transpose_cast_w<<<wt, 256, 0, stream>>>(Wv, Wqkv + 2*WELEMS);
    transpose_cast_w<<<wt, 256, 0, stream>>>(Wo, Wto);
    concat_bias<<<9, 256, 0, stream>>>(bq, bk, bv, bqkv);

    // 2. fused QKV projection (Q,K per-head; V direct-transposed)
    gemm8<MDIM, 2304, EDIM, EDIM, 4, 2304><<<2304, 512, 0, stream>>>(
        xb, Wqkv, bqkv, scaling, nullptr, Qp, 0, 0);

    // 3. attn logits, split-K=4: per head 512x512, K-chunks of 2048
    gemm8<CDIM, CDIM, 2048, 8192, 2, 192><<<192, 512, 0, stream>>>(
        Qp, Kp, nullptr, 1.f, part, nullptr, HSTRIDE, HSTRIDE);

    // 4. softmax (+4-way partial reduce), fp32 out + bf16 copy
    softmax_reduce<<<HDIM*CDIM, 256, 0, stream>>>(part, attnp, Pb);

    // 5. context: per head 512x8192xK512 -> bf16 token-major
    gemm8<CDIM, 8192, CDIM, CDIM, 3, 768><<<768, 512, 0, stream>>>(
        Pb, Vt, nullptr, 1.f, nullptr, ctxb, (size_t)CDIM*CDIM, HSTRIDE);

    // 6. output projection (fp32 + bias)
    gemm8<MDIM, EDIM, EDIM, EDIM, 1, 768><<<768, 512, 0, stream>>>(
        ctxb, Wto, bo, 1.f, out, nullptr, 0, 0);
}

// Round 9
// 581.820 us; speedup vs baseline: 1.4751x; 1.0103x over previous
//
#include <hip/hip_runtime.h>
#include <math.h>

#define RDIM 128
#define CDIM 512
#define EDIM 768
#define HDIM 12
#define DDIM 64
#define MDIM (RDIM*CDIM)                  // 65536 tokens
#define OUT_ELEMS ((size_t)MDIM*EDIM)     // 50331648
#define HSTRIDE ((size_t)CDIM*RDIM*DDIM)  // 4194304 elems per head (512*8192)
#define WELEMS (EDIM*EDIM)                // 589824

typedef unsigned short ushort_t;
typedef __attribute__((ext_vector_type(8))) short bf16x8;
typedef __attribute__((ext_vector_type(8))) unsigned short u16x8;
typedef __attribute__((ext_vector_type(4))) float f32x4;

__device__ __forceinline__ ushort_t f2bf(float f) {
    unsigned u = __float_as_uint(f);
    unsigned r = u + 0x7fffu + ((u >> 16) & 1u);   // round-to-nearest-even
    return (ushort_t)(r >> 16);
}

__device__ __forceinline__ void gload16(const void* g, void* l) {
    __builtin_amdgcn_global_load_lds(
        (const __attribute__((address_space(1))) unsigned int*)g,
        (__attribute__((address_space(3))) unsigned int*)l, 16, 0, 0);
}

// ============================================================================
// cast x (fp32) -> bf16, 8 elems/thread
// ============================================================================
__global__ __launch_bounds__(256)
void cast_x(const float* __restrict__ x, ushort_t* __restrict__ xb) {
    size_t i = ((size_t)blockIdx.x * 256 + threadIdx.x) * 8;
    float4 a = *(const float4*)&x[i];
    float4 b = *(const float4*)&x[i + 4];
    u16x8 o;
    o[0]=f2bf(a.x); o[1]=f2bf(a.y); o[2]=f2bf(a.z); o[3]=f2bf(a.w);
    o[4]=f2bf(b.x); o[5]=f2bf(b.y); o[6]=f2bf(b.z); o[7]=f2bf(b.w);
    *(u16x8*)&xb[i] = o;
}

// ============================================================================
// W[k][n] fp32 -> Wt[n][k] bf16   (768x768)
// ============================================================================
__global__ __launch_bounds__(256)
void transpose_cast_w(const float* __restrict__ W, ushort_t* __restrict__ Wt) {
    __shared__ ushort_t t[64][66];
    const int k0 = blockIdx.x * 64, n0 = blockIdx.y * 64;
    const int tx = threadIdx.x & 15, ty = threadIdx.x >> 4;
    #pragma unroll
    for (int rep = 0; rep < 4; ++rep) {
        int k = ty + rep * 16;
        float4 v = *(const float4*)&W[(size_t)(k0 + k) * EDIM + n0 + tx*4];
        t[k][tx*4+0] = f2bf(v.x); t[k][tx*4+1] = f2bf(v.y);
        t[k][tx*4+2] = f2bf(v.z); t[k][tx*4+3] = f2bf(v.w);
    }
    __syncthreads();
    #pragma unroll
    for (int rep = 0; rep < 4; ++rep) {
        int n = ty + rep * 16;
        ushort4 o = { t[tx*4+0][n], t[tx*4+1][n], t[tx*4+2][n], t[tx*4+3][n] };
        *(ushort4*)&Wt[(size_t)(n0 + n) * EDIM + k0 + tx*4] = o;
    }
}

// ============================================================================
// concat biases -> bqkv[2304] fp32
// ============================================================================
__global__ __launch_bounds__(256)
void concat_bias(const float* __restrict__ bq, const float* __restrict__ bk,
                 const float* __restrict__ bv, float* __restrict__ bqkv) {
    int i = blockIdx.x * 256 + threadIdx.x;
    if (i < 768)        bqkv[i] = bq[i];
    else if (i < 1536)  bqkv[i] = bk[i - 768];
    else if (i < 2304)  bqkv[i] = bv[i - 1536];
}

// ============================================================================
// 8-phase 256x256 BT-GEMM, BK=64, 512 thr = 8 waves (2M x 4N), 128x64/wave.
// acc[8 m-frags][4 n-frags]. Balanced phases (reads 12/4/8/0), NO forced
// lgkmcnt(0) — ds_reads are compiler-visible, compiler emits counted lgkm
// interleave within each phase (removing the m141-style pin). Hard phase
// boundaries kept: sched_barrier(0) + raw s_barrier (slot ledger safety).
// Phase plan per K-tile t:
//   P0: ds A(mq0) 8 + ds B(nq0) 4 -> MFMA(mq0,nq0)
//   P1: ds B(nq1) 4               -> MFMA(mq0,nq1)
//   P2: ds A(mq1) 8, stage B0+B1(t+2) -> MFMA(mq1,nq0)
//   P3: stage A0+A1(t+2)          -> MFMA(mq1,nq1); vmcnt(8)
// Ledger: B slots last-read P1 (stage lands >=P2+200cy); A slots last-read
// P2 (stage P3). vmcnt(8) at P3 -> tile t+1's 8 loads landed. Tail: tile
// NT-2 (vmcnt(0) at its P3), tile NT-1 plain.
// T2 swizzle: linear LDS dest, source seg^=(row&7), read col ^sw.
// T1 bijective XCD swizzle on flat grid, reuse dim innermost.
// MODE 1: out proj fp32+bias, w = mt*3+nt                  (NWG=768)
// MODE 2: split-K8 logits fp32, w = plane*4 + mt*2+nt      (NWG=384, K=1024)
// MODE 3: context bf16 token-major, w = h*64 + mt*32 + nt  (NWG=768)
// MODE 4: fused QKV, w = mt*9 + ntile                      (NWG=2304)
// ============================================================================
#define SBAR do { __builtin_amdgcn_sched_barrier(0); \
                  __builtin_amdgcn_s_barrier(); \
                  __builtin_amdgcn_sched_barrier(0); } while(0)
#define SCHED0 __builtin_amdgcn_sched_barrier(0)
#define VMCNT(n_) asm volatile("s_waitcnt vmcnt(" #n_ ")" ::: "memory")

template<int M, int N, int K, int LDK, int MODE, int NWG>
__global__ __launch_bounds__(512, 2)
void gemm8(const ushort_t* __restrict__ A, const ushort_t* __restrict__ B,
           const float* __restrict__ bias, float scale,
           float* __restrict__ outF, ushort_t* __restrict__ outB,
           size_t sAh, size_t sBh) {
    __shared__ __align__(16) char smem[131072];
    constexpr int NT = K / 64;

    const int tid = threadIdx.x;
    const int lane = tid & 63, wid = tid >> 6;
    const int wr = wid >> 2, wc = wid & 3;          // 2M x 4N wave grid
    const int fr = lane & 15, fs = lane >> 4;
    const int sw = (fr & 7) << 3;

    const int bid = blockIdx.x;
    const int w = (bid & 7) * (NWG / 8) + (bid >> 3);
    int bm, bn, h = 0, ksub = 0, plane = 0, ntile = 0;
    if (MODE == 4)      { ntile = w % 9; bm = (w / 9) * 256; bn = ntile * 256; }
    else if (MODE == 2) { plane = w >> 2; h = plane >> 3; ksub = plane & 7;
                          bm = ((w >> 1) & 1) * 256; bn = (w & 1) * 256; }
    else if (MODE == 3) { h = w >> 6; bm = ((w >> 5) & 1) * 256; bn = (w & 31) * 256; }
    else                { bm = (w / 3) * 256; bn = (w % 3) * 256; }

    const ushort_t* Ab = A + (MODE == 2 || MODE == 3 ? (size_t)h * sAh : 0)
                       + (MODE == 2 ? (size_t)ksub * K : 0) + (size_t)bm * LDK;
    const ushort_t* Bb = B + (MODE == 2 || MODE == 3 ? (size_t)h * sBh : 0)
                       + (MODE == 2 ? (size_t)ksub * K : 0) + (size_t)bn * LDK;

    // staging: half-tile = 128 rows x 64 cols; 2 gload16/thread
    const int r0 = tid >> 3, s0 = tid & 7;
    const size_t gO0 = (size_t)r0 * LDK + ((s0 ^ (r0 & 7)) * 8);
    const size_t gO1 = gO0 + (size_t)64 * LDK;      // (row+64)&7 == row&7
    const int l0 = tid * 16, l1 = tid * 16 + 8192;

#define STAGE_A(t_, h_) do { \
    char* d_ = smem + ((((t_) & 1) * 2 + (h_)) * 16384); \
    const ushort_t* s_ = Ab + (size_t)((h_) * 128) * LDK + (t_) * 64; \
    gload16(s_ + gO0, d_ + l0); gload16(s_ + gO1, d_ + l1); } while(0)
#define STAGE_B(t_, h_) do { \
    char* d_ = smem + 65536 + ((((t_) & 1) * 2 + (h_)) * 16384); \
    const ushort_t* s_ = Bb + (size_t)((h_) * 128) * LDK + (t_) * 64; \
    gload16(s_ + gO0, d_ + l0); gload16(s_ + gO1, d_ + l1); } while(0)

    f32x4 acc[8][4];
    #pragma unroll
    for (int i = 0; i < 8; ++i)
        #pragma unroll
        for (int j = 0; j < 4; ++j) acc[i][j] = (f32x4){0.f, 0.f, 0.f, 0.f};
    bf16x8 a_[4][2], bb0_[2][2], bb1_[2][2];

#define DSA(t_, mq_) do { \
    const ushort_t* As_ = (const ushort_t*)(smem + ((((t_) & 1) * 2 + wr) * 16384)); \
    _Pragma("unroll") for (int f = 0; f < 4; ++f) \
      _Pragma("unroll") for (int kk = 0; kk < 2; ++kk) \
        a_[f][kk] = *(const bf16x8*)&As_[((mq_) * 64 + f * 16 + fr) * 64 \
                                          + ((kk * 32 + fs * 8) ^ sw)]; } while(0)

#define DSB(t_, nq_, B_) do { \
    const ushort_t* Bs_ = (const ushort_t*)(smem + 65536 + ((((t_) & 1) * 2 + (wc >> 1)) * 16384)); \
    _Pragma("unroll") for (int nf = 0; nf < 2; ++nf) \
      _Pragma("unroll") for (int kk = 0; kk < 2; ++kk) \
        B_[nf][kk] = *(const bf16x8*)&Bs_[((wc & 1) * 64 + (nq_) * 32 + nf * 16 + fr) * 64 \
                                           + ((kk * 32 + fs * 8) ^ sw)]; } while(0)

#define MFMA8(mq_, nq_, B_) do { \
    __builtin_amdgcn_s_setprio(1); \
    _Pragma("unroll") for (int f = 0; f < 4; ++f) \
      _Pragma("unroll") for (int nf2 = 0; nf2 < 2; ++nf2) \
        _Pragma("unroll") for (int kk = 0; kk < 2; ++kk) \
          acc[(mq_) * 4 + f][(nq_) * 2 + nf2] = __builtin_amdgcn_mfma_f32_16x16x32_bf16( \
              a_[f][kk], B_[nf2][kk], acc[(mq_) * 4 + f][(nq_) * 2 + nf2], 0, 0, 0); \
    __builtin_amdgcn_s_setprio(0); } while(0)

    // ---- prologue: stage tiles 0 and 1 (16 loads/thread), order-pinned ----
    STAGE_B(0, 0); SCHED0;
    STAGE_B(0, 1); SCHED0;
    STAGE_A(0, 0); SCHED0;
    STAGE_A(0, 1); SCHED0;
    STAGE_B(1, 0); SCHED0;
    STAGE_B(1, 1); SCHED0;
    STAGE_A(1, 0); SCHED0;
    STAGE_A(1, 1); SCHED0;
    VMCNT(8);                       // tile 0's 8 halves landed
    SBAR;

    // ---- main loop ----
    for (int t = 0; t < NT - 2; ++t) {
        // P0
        DSA(t, 0); DSB(t, 0, bb0_);
        MFMA8(0, 0, bb0_);
        SBAR;
        // P1
        DSB(t, 1, bb1_);
        MFMA8(0, 1, bb1_);
        SBAR;
        // P2
        DSA(t, 1);
        STAGE_B(t + 2, 0); STAGE_B(t + 2, 1);
        MFMA8(1, 0, bb0_);
        SBAR;
        // P3
        STAGE_A(t + 2, 0); STAGE_A(t + 2, 1);
        MFMA8(1, 1, bb1_);
        VMCNT(8);                   // tile t+1's 8 halves landed
        SBAR;
    }

    // ---- tail: tile NT-2 (drain at end), tile NT-1 plain ----
    {
        const int t = NT - 2;
        DSA(t, 0); DSB(t, 0, bb0_); MFMA8(0, 0, bb0_); SBAR;
        DSB(t, 1, bb1_);            MFMA8(0, 1, bb1_); SBAR;
        DSA(t, 1);                  MFMA8(1, 0, bb0_); SBAR;
        MFMA8(1, 1, bb1_);
        VMCNT(0);                   // tile NT-1's loads landed
        SBAR;
        const int u = NT - 1;
        DSA(u, 0); DSB(u, 0, bb0_); MFMA8(0, 0, bb0_); SBAR;
        DSB(u, 1, bb1_);            MFMA8(0, 1, bb1_); SBAR;
        DSA(u, 1);                  MFMA8(1, 0, bb0_); SBAR;
        MFMA8(1, 1, bb1_);
    }

    // ---- epilogues ----
    if (MODE == 4) {
        const int which = ntile / 3;               // 0=Q,1=K,2=V
        const int hcb = (ntile % 3) * 256;         // hcol base
        if (which < 2) {
            ushort_t* dst = outB + (size_t)which * OUT_ELEMS;
            const float sc = (which == 0) ? scale : 1.f;
            #pragma unroll
            for (int mf = 0; mf < 8; ++mf) {
                #pragma unroll
                for (int nf = 0; nf < 4; ++nf) {
                    const int hcol = hcb + wc*64 + nf*16 + fr;
                    const float bv = bias[which*768 + hcol];
                    const int hh = hcol >> 6, d = hcol & 63;
                    #pragma unroll
                    for (int j = 0; j < 4; ++j) {
                        const int m = bm + wr*128 + mf*16 + fs*4 + j;
                        float v = (acc[mf][nf][j] + bv) * sc;
                        size_t addr = (size_t)hh * HSTRIDE
                                    + (size_t)(m & 511) * 8192 + (m >> 9) * 64 + d;
                        dst[addr] = f2bf(v);
                    }
                }
            }
        } else {
            // V: transpose via LDS (2 passes of 128 n-rows), coalesced to Vt
            ushort_t* Ts = (ushort_t*)smem;        // [128][264] = 67.6 KB
            ushort_t* dst = outB + 2 * OUT_ELEMS;
            const int rblk = bm >> 9, jb = bm & 511;
            __syncthreads();
            #pragma unroll
            for (int q = 0; q < 2; ++q) {
                if ((wc >> 1) == q) {
                    #pragma unroll
                    for (int mf = 0; mf < 8; ++mf) {
                        #pragma unroll
                        for (int nf = 0; nf < 4; ++nf) {
                            const int nl = wc*64 + nf*16 + fr;
                            const float bv = bias[1536 + hcb + nl];
                            #pragma unroll
                            for (int j = 0; j < 4; ++j)
                                Ts[(nl & 127)*264 + wr*128 + mf*16 + fs*4 + j] =
                                    f2bf(acc[mf][nf][j] + bv);
                        }
                    }
                }
                __syncthreads();
                #pragma unroll
                for (int it = 0; it < 8; ++it) {
                    const int idx = it * 512 + tid;
                    const int row = idx >> 5, c8 = (idx & 31) * 8;
                    const int nl = q*128 + row;
                    const int hh = (hcb + nl) >> 6, d = nl & 63;
                    uint4 wv;
                    wv.x = *(const uint*)&Ts[row*264 + c8];
                    wv.y = *(const uint*)&Ts[row*264 + c8 + 2];
                    wv.z = *(const uint*)&Ts[row*264 + c8 + 4];
                    wv.w = *(const uint*)&Ts[row*264 + c8 + 6];
                    size_t addr = (size_t)hh * HSTRIDE
                                + (size_t)(rblk*64 + d) * CDIM + jb + c8;
                    *(uint4*)&dst[addr] = wv;
                }
                __syncthreads();
            }
        }
        return;
    }

    #pragma unroll
    for (int mf = 0; mf < 8; ++mf) {
        #pragma unroll
        for (int nf = 0; nf < 4; ++nf) {
            const int n = bn + wc*64 + nf*16 + fr;
            float bv = (MODE == 1) ? bias[n] : 0.f;
            #pragma unroll
            for (int j = 0; j < 4; ++j) {
                const int m = bm + wr*128 + mf*16 + fs*4 + j;
                float v = acc[mf][nf][j];
                if (MODE == 1) {
                    outF[(size_t)m * N + n] = v + bv;
                } else if (MODE == 2) {
                    outF[(size_t)plane * (CDIM*CDIM) + (size_t)m * CDIM + n] = v;
                } else { // MODE 3
                    size_t addr = ((size_t)(n >> 6) * CDIM + m) * EDIM
                                + h * DDIM + (n & 63);
                    outB[addr] = f2bf(v);
                }
            }
        }
    }
}

// ============================================================================
// softmax over 512 cols for H*C rows; sums 8 split-K partials first.
// fp32 probs -> attn (d_out), bf16 copy -> Pb.
// ============================================================================
__global__ __launch_bounds__(256)
void softmax_reduce(const float* __restrict__ part, float* __restrict__ attn,
                    ushort_t* __restrict__ Pb) {
    const int row = blockIdx.x;              // h*512 + c
    const int h = row >> 9, c = row & 511;
    const int tid = threadIdx.x;
    const int lane = tid & 63, wid = tid >> 6;
    __shared__ float red[8];

    float v0 = 0.f, v1 = 0.f;
    #pragma unroll
    for (int s = 0; s < 8; ++s) {
        const float* p = part + ((size_t)(h*8 + s) * (CDIM*CDIM)) + (size_t)c * CDIM;
        v0 += p[tid];
        v1 += p[tid + 256];
    }
    float m = fmaxf(v0, v1);
    #pragma unroll
    for (int off = 32; off > 0; off >>= 1) m = fmaxf(m, __shfl_down(m, off));
    if (lane == 0) red[wid] = m;
    __syncthreads();
    if (tid == 0) red[4] = fmaxf(fmaxf(red[0], red[1]), fmaxf(red[2], red[3]));
    __syncthreads();
    const float M = red[4];

    float e0 = expf(v0 - M), e1 = expf(v1 - M);
    float s = e0 + e1;
    #pragma unroll
    for (int off = 32; off > 0; off >>= 1) s += __shfl_down(s, off);
    __syncthreads();
    if (lane == 0) red[wid] = s;
    __syncthreads();
    if (tid == 0) red[5] = red[0] + red[1] + red[2] + red[3];
    __syncthreads();
    const float inv = 1.f / red[5];
    float o0 = e0 * inv, o1 = e1 * inv;
    float* pout = attn + (size_t)row * CDIM;
    ushort_t* pb = Pb + (size_t)row * CDIM;
    pout[tid] = o0;        pout[tid + 256] = o1;
    pb[tid]   = f2bf(o0);  pb[tid + 256]   = f2bf(o1);
}

// ============================================================================
extern "C" void kernel_launch(void* const* d_in, const int* in_sizes, int n_in,
                              void* d_out, int out_size, void* d_ws, size_t ws_size,
                              hipStream_t stream) {
    const float* x  = (const float*)d_in[0];
    const float* Wq = (const float*)d_in[1];
    const float* bq = (const float*)d_in[2];
    const float* Wk = (const float*)d_in[3];
    const float* bk = (const float*)d_in[4];
    const float* Wv = (const float*)d_in[5];
    const float* bv = (const float*)d_in[6];
    const float* Wo = (const float*)d_in[7];
    const float* bo = (const float*)d_in[8];

    float* out   = (float*)d_out;
    float* attnp = out + OUT_ELEMS;            // attn_probs fp32 output region

    // workspace layout (ushort units)
    ushort_t* ws   = (ushort_t*)d_ws;
    ushort_t* xb   = ws;                                   // 100.66 MB
    ushort_t* Wqkv = xb + OUT_ELEMS;                       // [2304][768]
    ushort_t* Wto  = Wqkv + 3*WELEMS;
    float*    bqkv = (float*)(Wto + WELEMS);               // 2304 fp32
    ushort_t* Qp   = Wto + WELEMS + 4608;                  // [12][512][8192]
    ushort_t* Kp   = Qp + OUT_ELEMS;                       // contiguous after Qp
    ushort_t* Vt   = Kp + OUT_ELEMS;                       // [12][8192][512]
    ushort_t* Pb   = Vt + OUT_ELEMS;                       // [12][512][512]
    // xb is dead after QKV; its 100.66MB region hosts the 96 split-K partial
    // planes (96*512*512*4B = 100.66MB exactly), then the ctx output.
    float*    part = (float*)xb;
    ushort_t* ctxb = xb;

    const float scaling = 0.011048543456039806f;  // 64^-0.5 / sqrt(128)

    // 1. casts / weight transposes / bias concat
    cast_x<<<MDIM*EDIM/(256*8), 256, 0, stream>>>(x, xb);
    dim3 wt(EDIM/64, EDIM/64);
    transpose_cast_w<<<wt, 256, 0, stream>>>(Wq, Wqkv);
    transpose_cast_w<<<wt, 256, 0, stream>>>(Wk, Wqkv + WELEMS);
    transpose_cast_w<<<wt, 256, 0, stream>>>(Wv, Wqkv + 2*WELEMS);
    transpose_cast_w<<<wt, 256, 0, stream>>>(Wo, Wto);
    concat_bias<<<9, 256, 0, stream>>>(bq, bk, bv, bqkv);

    // 2. fused QKV projection (Q,K per-head; V direct-transposed)
    gemm8<MDIM, 2304, EDIM, EDIM, 4, 2304><<<2304, 512, 0, stream>>>(
        xb, Wqkv, bqkv, scaling, nullptr, Qp, 0, 0);

    // 3. attn logits, split-K=8: per head 512x512, K-chunks of 1024
    gemm8<CDIM, CDIM, 1024, 8192, 2, 384><<<384, 512, 0, stream>>>(
        Qp, Kp, nullptr, 1.f, part, nullptr, HSTRIDE, HSTRIDE);

    // 4. softmax (+8-way partial reduce), fp32 out + bf16 copy
    softmax_reduce<<<HDIM*CDIM, 256, 0, stream>>>(part, attnp, Pb);

    // 5. context: per head 512x8192xK512 -> bf16 token-major
    gemm8<CDIM, 8192, CDIM, CDIM, 3, 768><<<768, 512, 0, stream>>>(
        Pb, Vt, nullptr, 1.f, nullptr, ctxb, (size_t)CDIM*CDIM, HSTRIDE);

    // 6. output projection (fp32 + bias)
    gemm8<MDIM, EDIM, EDIM, EDIM, 1, 768><<<768, 512, 0, stream>>>(
        ctxb, Wto, bo, 1.f, out, nullptr, 0, 0);
}